// Round 7
// baseline (264.127 us; speedup 1.0000x reference)
//
#include <hip/hip_runtime.h>
#include <hip/hip_cooperative_groups.h>

#pragma clang fp contract(off)

namespace cg = cooperative_groups;

namespace {
constexpr int NB = 2, ND = 100, MH = 28, MW = 28;
constexpr int OH = 512, OW = 512;
constexpr int SH = 128, SW = 128, NC = 32;
constexpr int BMP_ROWS = 172;
constexpr int BMP8_ROWWORDS = 8;                        // canvas-aligned words per row
constexpr int BMP8_DETWORDS = BMP_ROWS * BMP8_ROWWORDS; // 1376

// workspace layout (int32 word indices)
constexpr int OFF_COUNTS = 0;                     // NB*32
constexpr int OFF_AREA   = 64;                    // NB*ND
constexpr int OFF_ACC    = OFF_AREA + NB*ND;
constexpr int OFF_YB     = OFF_ACC  + NB*ND;
constexpr int OFF_VAL    = OFF_YB   + NB*ND;
constexpr int OFF_QN     = OFF_VAL  + NB*ND;
constexpr int OFF_SEGCLS = OFF_QN   + NB*ND;      // byte region: NB*OH*OW bytes
constexpr int OFF_BMP8   = OFF_SEGCLS + (NB*OH*OW)/4;
constexpr int OCC_STRIDE = 25;                    // odd -> conflict-free; q0+7 <= 22 < 25
constexpr int OCC_WORDS  = OH * OCC_STRIDE;       // 12800 words = 51.2 KB
static_assert(OFF_BMP8 % 4 == 0, "uint4 alignment");

struct SegSh  { float patch[NC*342]; };                          // [ch][18 rows * 19 stride]
struct MaskSh { float sc[ND]; float sm[MH*MW]; int det; int area; };
struct ScanSh { unsigned int occ[OCC_WORDS]; int list[ND], area[ND], yb[ND], q0[ND]; };
struct HistSh { unsigned int h[NC]; };
struct ResSh  { int val[ND]; int cnt[NC]; };
union AllSh   { SegSh seg; MaskSh mask; ScanSh scan; HistSh hist; ResSh res; };
}

// ---------------- seg tile: 64x64 out px, LDS-staged 18x18x32 patch ----------------
__device__ __forceinline__ void segTile(int tid, int t, const float* __restrict__ segp,
                                        int* __restrict__ wsI, int* __restrict__ out,
                                        SegSh& S) {
  const int b  = tid >> 6;
  const int tl = tid & 63;
  const int oy = (tl >> 3) * 64, ox = (tl & 7) * 64;
  const int iy0 = (oy >> 2) - 1, ix0 = (ox >> 2) - 1;
  // stage patch: 18x18 px x 8 float4
  for (int idx = t; idx < 18*18*8; idx += 256) {
    const int w  = idx & 7, px = idx >> 3;
    const int pr = px / 18, pc = px - pr*18;
    const int gy = min(max(iy0 + pr, 0), SH-1);
    const int gx = min(max(ix0 + pc, 0), SW-1);
    const float4 v = *(const float4*)(segp + (size_t)((b*SH + gy)*SW + gx)*NC + w*4);
    const int base = pr*19 + pc;
    S.patch[(w*4+0)*342 + base] = v.x;
    S.patch[(w*4+1)*342 + base] = v.y;
    S.patch[(w*4+2)*342 + base] = v.z;
    S.patch[(w*4+3)*342 + base] = v.w;
  }
  __syncthreads();
  const int ty2 = t >> 4, tx2 = t & 15;
  // per-output-row/col tables (weights are exact eighths; clamp -> f=0 single-tap exact)
  int rlo[4], rhi[4], clo[4], chi[4];
  float fy[4], wy[4], fx[4], wx[4];
  #pragma unroll
  for (int u = 0; u < 4; ++u) {
    const int Y = oy + ty2*4 + u;
    float my = ((float)Y + 0.5f)*0.25f - 0.5f;
    float y0f = floorf(my);
    float f = my - y0f;
    int y0 = (int)y0f, y1 = y0 + 1;
    if (y0 < 0)           { y0 = 0; y1 = 0; f = 0.0f; }
    else if (y1 > SH - 1) { y1 = SH - 1; f = 0.0f; }
    rlo[u] = y0 - iy0; rhi[u] = y1 - iy0; fy[u] = f; wy[u] = 1.0f - f;
  }
  #pragma unroll
  for (int v = 0; v < 4; ++v) {
    const int X = ox + tx2*4 + v;
    float mx = ((float)X + 0.5f)*0.25f - 0.5f;
    float x0f = floorf(mx);
    float f = mx - x0f;
    int x0 = (int)x0f, x1 = x0 + 1;
    if (x0 < 0)           { x0 = 0; x1 = 0; f = 0.0f; }
    else if (x1 > SW - 1) { x1 = SW - 1; f = 0.0f; }
    clo[v] = x0 - ix0; chi[v] = x1 - ix0; fx[v] = f; wx[v] = 1.0f - f;
  }
  const int ro[4] = { rlo[0]*19, rhi[0]*19, rlo[2]*19, rhi[2]*19 };  // u01 pair, u23 pair
  const int co[4] = { clo[0],    chi[0],    clo[2],    chi[2]    };
  float best[4][4]; int bcls[4][4];
  #pragma unroll
  for (int u = 0; u < 4; ++u)
    #pragma unroll
    for (int v = 0; v < 4; ++v) { best[u][v] = -3.4e38f; bcls[u][v] = 0; }
  for (int ch = 0; ch < NC; ++ch) {
    const float* P = S.patch + ch*342;
    float tv[4][4];
    #pragma unroll
    for (int i = 0; i < 4; ++i)
      #pragma unroll
      for (int j = 0; j < 4; ++j)
        tv[i][j] = P[ro[i] + co[j]];
    float V[4][4];
    #pragma unroll
    for (int u = 0; u < 4; ++u) {
      const int lo = (u < 2) ? 0 : 2;
      #pragma unroll
      for (int j = 0; j < 4; ++j)
        V[u][j] = wy[u]*tv[lo][j] + fy[u]*tv[lo+1][j];   // vertical first (matches ref)
    }
    #pragma unroll
    for (int u = 0; u < 4; ++u)
      #pragma unroll
      for (int v = 0; v < 4; ++v) {
        const int lo = (v < 2) ? 0 : 2;
        float val = wx[v]*V[u][lo] + fx[v]*V[u][lo+1];
        if (val > best[u][v]) { best[u][v] = val; bcls[u][v] = ch; }  // strict > = first max
      }
  }
  unsigned int* segclsW = (unsigned int*)((char*)wsI + (size_t)OFF_SEGCLS*4);
  const uint4 sent = uint4{0x7FFFFFFFu,0x7FFFFFFFu,0x7FFFFFFFu,0x7FFFFFFFu};
  #pragma unroll
  for (int u = 0; u < 4; ++u) {
    const int Y = oy + ty2*4 + u, X = ox + tx2*4;
    const int pidw = (b*OH*OW + Y*OW + X) >> 2;
    segclsW[pidw] = (unsigned)bcls[u][0] | ((unsigned)bcls[u][1]<<8)
                  | ((unsigned)bcls[u][2]<<16) | ((unsigned)bcls[u][3]<<24);
    *(uint4*)(out + b*OH*OW + Y*OW + X) = sent;          // owner sentinel
  }
}

// ---------------- mask: per-det canvas-aligned bitmap + area (rank local) ----------------
__device__ __forceinline__ void maskOne(int g, int t, const float* __restrict__ boxes,
                                        const int* __restrict__ classes,
                                        const float* __restrict__ scores,
                                        const float* __restrict__ dmasks,
                                        int* __restrict__ wsI, MaskSh& M) {
  const int b = g / ND, k = g - b*ND;
  if (t < ND) M.sc[t] = scores[b*ND + t];
  if (t == 0) M.area = 0;
  __syncthreads();
  if (t < ND) {
    float sn = M.sc[t];
    int r = 0;
    for (int j = 0; j < ND; ++j) {
      float sj = M.sc[j];
      r += (sj > sn) || (sj == sn && j < t);   // stable descending rank
    }
    if (r == k) M.det = t;
  }
  __syncthreads();
  const int det = M.det;
  const int cls = classes[b*ND + det];
  const float sc = M.sc[det];
  const float* bx = boxes + (size_t)(b*ND + det)*4;
  const float ymin = bx[0], xmin = bx[1], ymax = bx[2], xmax = bx[3];
  const bool keep = (sc > 0.5f) && (cls != 0);
  int ylo = (int)ceilf(ymin), yhi = (int)ceilf(ymax);
  int xlo = (int)ceilf(xmin), xhi = (int)ceilf(xmax);
  ylo = max(ylo, 0); xlo = max(xlo, 0);
  yhi = min(yhi, OH); xhi = min(xhi, OW);
  if (yhi < ylo) yhi = ylo;
  if (xhi < xlo) xhi = xlo;
  if (yhi - ylo > BMP_ROWS) yhi = ylo + BMP_ROWS;
  if (xhi - xlo > 192)      xhi = xlo + 192;
  int yhi2 = keep ? yhi : ylo, xhi2 = keep ? xhi : xlo;
  const int rows = yhi2 - ylo, width = xhi2 - xlo;
  const int q0 = xlo >> 5;
  const int nw = (width > 0) ? (((xlo & 31) + width + 31) >> 5) : 0;
  if (t == 0) {
    wsI[OFF_YB  + g] = ylo | (yhi2 << 16);
    wsI[OFF_VAL + g] = (det + 1) | (cls << 16);
    wsI[OFF_QN  + g] = q0 | (nw << 16);
  }
  if (rows > 0 && width > 0) {               // uniform branch
    const float hs  = (ymax > ymin) ? (28.0f / (ymax - ymin)) : 0.0f;
    const float wsc = (xmax > xmin) ? (28.0f / (xmax - xmin)) : 0.0f;
    const float* mp = dmasks + (size_t)(b*ND + det)*(MH*MW);
    for (int i = t; i < MH*MW; i += 256) M.sm[i] = mp[i];
    __syncthreads();
    unsigned int* bmp8 = (unsigned int*)wsI + OFF_BMP8 + g*BMP8_DETWORDS;
    const int iw = t >> 5, bit = t & 31;
    const int x = ((q0 + iw) << 5) + bit;
    const bool inbox = (x >= xlo) && (x < xhi2);
    for (int r = 0; r < rows; ++r) {
      const int y = ylo + r;
      bool pred = false;
      if (inbox) {
        // exact op order of _paste_one (fp contract off)
        float ty = ((float)y + 0.5f); ty = ty - ymin; ty = ty * hs;  float my = ty - 0.5f;
        float tx = ((float)x + 0.5f); tx = tx - xmin; tx = tx * wsc; float mx = tx - 0.5f;
        float y0f = floorf(my), x0f = floorf(mx);
        float ly = my - y0f, lx = mx - x0f;
        int y0 = (int)y0f, x0 = (int)x0f;
        int y1 = min(max(y0 + 1, 0), MH - 1);
        int x1 = min(max(x0 + 1, 0), MW - 1);
        y0 = min(max(y0, 0), MH - 1);
        x0 = min(max(x0, 0), MW - 1);
        float v00 = M.sm[y0*MW + x0], v01 = M.sm[y0*MW + x1];
        float v10 = M.sm[y1*MW + x0], v11 = M.sm[y1*MW + x1];
        float omlx = 1.0f - lx, omly = 1.0f - ly;
        float top = omlx*v00 + lx*v01;
        float bot = omlx*v10 + lx*v11;
        float outv = omly*top + ly*bot;
        pred = outv > 0.5f;
      }
      unsigned long long m = __ballot(pred);
      unsigned int word = (t & 32) ? (unsigned int)(m >> 32) : (unsigned int)m;
      if (bit == 0) {
        bmp8[r*BMP8_ROWWORDS + iw] = word;
        if (word) atomicAdd(&M.area, __popc(word));
      }
    }
  }
  __syncthreads();
  if (t == 0) wsI[OFF_AREA + g] = (rows > 0 && width > 0) ? M.area : 0;
}

// ---------------- scan helpers ----------------
__device__ __forceinline__ void loadDet(const uint4* __restrict__ base, int g, int t, int yb,
                                        uint4 lo[3], uint4 hi[3]) {
  const int rows = (yb >> 16) - (yb & 0xffff);
  const uint4* p = base + (size_t)g*(BMP8_DETWORDS/4);
  #pragma unroll
  for (int j = 0; j < 3; ++j) {
    const int rr = t + j*64;
    if (rr < rows) { lo[j] = p[rr*2 + 0]; hi[j] = p[rr*2 + 1]; }
    else           { lo[j] = uint4{0,0,0,0}; hi[j] = uint4{0,0,0,0}; }
  }
}

__device__ __forceinline__ void processDet(int t, const uint4 lo[3], const uint4 hi[3],
                                           unsigned int* occ, int area, int yb, int q0,
                                           int* __restrict__ accp) {
  const int ylo = yb & 0xffff;
  const int rows = (yb >> 16) - ylo;
  unsigned int w[3][8], o[3][8];
  int rb_[3];
  int cnt = 0;
  #pragma unroll
  for (int j = 0; j < 3; ++j) {
    const int rr = t + j*64;
    if (rr < rows) {                        // exec-masked; fully-dead quarters skipped
      const int rb = (ylo + rr) * OCC_STRIDE + q0;
      rb_[j] = rb;
      w[j][0] = lo[j].x; w[j][1] = lo[j].y; w[j][2] = lo[j].z; w[j][3] = lo[j].w;
      w[j][4] = hi[j].x; w[j][5] = hi[j].y; w[j][6] = hi[j].z; w[j][7] = hi[j].w;
      #pragma unroll
      for (int i = 0; i < 8; ++i) {
        const unsigned int ov = occ[rb + i];
        cnt += __popc(w[j][i] & ov);
        o[j][i] = ov;
      }
    }
  }
  #pragma unroll
  for (int off = 32; off; off >>= 1) cnt += __shfl_xor(cnt, off);
  const bool acc = ((float)cnt / (float)area) < 0.5f;   // area>=1 (compacted list)
  if (acc) {
    if (t == 0) *accp = 1;
    #pragma unroll
    for (int j = 0; j < 3; ++j) {
      if (t + j*64 < rows) {
        #pragma unroll
        for (int i = 0; i < 8; ++i) occ[rb_[j] + i] = o[j][i] | w[j][i];
      }
    }
  }
}

// ================= the single cooperative kernel =================
__global__ void __launch_bounds__(256, 1)
k_fused(const float* __restrict__ boxes, const int* __restrict__ classes,
        const float* __restrict__ scores, const float* __restrict__ dmasks,
        const float* __restrict__ segp, int* __restrict__ wsI, int* __restrict__ out) {
  cg::grid_group grid = cg::this_grid();
  __shared__ AllSh sh;
  const int bid = blockIdx.x, t = threadIdx.x;

  // ---------- phase A: seg tiles (blocks 0..127) | masks (blocks 128..255) ----------
  if (bid < 128) {
    segTile(bid, t, segp, wsI, out, sh.seg);
  } else {
    for (int pass = 0; pass < 2; ++pass) {
      const int g = (bid - 128) + pass*128;
      if (g >= NB*ND) break;                 // uniform
      maskOne(g, t, boxes, classes, scores, dmasks, wsI, sh.mask);
      __syncthreads();
    }
  }
  grid.sync();

  // ---------- phase B: scan (blocks 0..1) | stuff histogram (blocks 2..129) ----------
  if (bid < NB) {
    const int b = bid;
    for (int i = t; i < OCC_WORDS; i += 256) sh.scan.occ[i] = 0u;
    for (int i = t; i < ND; i += 256) {
      sh.scan.area[i] = wsI[OFF_AREA + b*ND + i];
      sh.scan.yb[i]   = wsI[OFF_YB   + b*ND + i];
      sh.scan.q0[i]   = wsI[OFF_QN   + b*ND + i] & 0xffff;
      wsI[OFF_ACC + b*ND + i] = 0;
    }
    __syncthreads();
    if (t < 64) {
      int nact = 0;
      for (int base = 0; base < ND; base += 64) {
        const int i = base + t;
        const bool a = (i < ND) && (sh.scan.area[i] > 0);
        unsigned long long m = __ballot(a);
        int pos = nact + __popcll(m & ((1ull << t) - 1ull));
        if (a) sh.scan.list[pos] = i;
        nact += (int)__popcll(m);
      }
      if (nact > 0) {
        const uint4* bmp4 = (const uint4*)((unsigned int*)wsI + OFF_BMP8 + (size_t)b*ND*BMP8_DETWORDS);
        int* accB = wsI + OFF_ACC + b*ND;
        uint4 Alo[3], Ahi[3], Blo[3], Bhi[3], Clo[3], Chi[3];
        const int last = nact - 1;
        {
          const int g0 = sh.scan.list[0], g1 = sh.scan.list[min(1, last)];
          loadDet(bmp4, g0, t, sh.scan.yb[g0], Alo, Ahi);
          loadDet(bmp4, g1, t, sh.scan.yb[g1], Blo, Bhi);
        }
        for (int ii = 0; ii < nact; ii += 3) {
          const int gC = sh.scan.list[min(ii+2, last)];
          loadDet(bmp4, gC, t, sh.scan.yb[gC], Clo, Chi);
          { const int g = sh.scan.list[ii];
            processDet(t, Alo, Ahi, sh.scan.occ, sh.scan.area[g], sh.scan.yb[g], sh.scan.q0[g], accB + g); }
          const int gA = sh.scan.list[min(ii+3, last)];
          loadDet(bmp4, gA, t, sh.scan.yb[gA], Alo, Ahi);
          if (ii+1 < nact) { const int g = sh.scan.list[ii+1];
            processDet(t, Blo, Bhi, sh.scan.occ, sh.scan.area[g], sh.scan.yb[g], sh.scan.q0[g], accB + g); }
          const int gB = sh.scan.list[min(ii+4, last)];
          loadDet(bmp4, gB, t, sh.scan.yb[gB], Blo, Bhi);
          if (ii+2 < nact) { const int g = sh.scan.list[ii+2];
            processDet(t, Clo, Chi, sh.scan.occ, sh.scan.area[g], sh.scan.yb[g], sh.scan.q0[g], accB + g); }
        }
      }
    }
  } else if (bid < 130) {
    // 128 blocks x 1024 words of segcls bytes -> class counts
    const int cb = bid - 2;
    const int b = (cb >= 64) ? 1 : 0;
    if (t < NC) sh.hist.h[t] = 0u;
    __syncthreads();
    const unsigned int* segclsW = (const unsigned int*)((const char*)wsI + (size_t)OFF_SEGCLS*4);
    #pragma unroll
    for (int i = 0; i < 4; ++i) {
      unsigned int w = segclsW[cb*1024 + i*256 + t];
      #pragma unroll
      for (int by = 0; by < 4; ++by) {
        const int cls = (w >> (by*8)) & 0xff;
        if (cls >= 2) atomicAdd(&sh.hist.h[cls], 1u);
      }
    }
    __syncthreads();
    if (t < NC) {
      const unsigned int h = sh.hist.h[t];
      if (h) atomicAdd((unsigned int*)&wsI[OFF_COUNTS + b*32 + t], h);
    }
  }
  grid.sync();

  // ---------- phase C: paint owners via atomicMin (blocks 0..199) ----------
  if (bid < NB*ND) {
    const int g = bid;
    if (wsI[OFF_ACC + g]) {                  // uniform
      const int b = g / ND, k = g - b*ND;
      const int yb = wsI[OFF_YB + g];
      const int ylo = yb & 0xffff;
      const int rows = (yb >> 16) - ylo;
      const int q0 = wsI[OFF_QN + g] & 0xffff;
      const unsigned int* bmp = (const unsigned int*)wsI + OFF_BMP8 + g*BMP8_DETWORDS;
      int* __restrict__ owner = out + b*(OH*OW);
      const int iw = t >> 5, bit = t & 31;
      const int x = ((q0 + iw) << 5) + bit;
      if (x < OW) {
        for (int r = 0; r < rows; ++r) {
          const unsigned int wv = bmp[r*BMP8_ROWWORDS + iw];
          if ((wv >> bit) & 1u)
            atomicMin(&owner[(ylo + r)*OW + x], k);   // owner = min sorted rank == ref
        }
      }
    }
  }
  grid.sync();

  // ---------- phase D: resolve owner -> inst/cat, else stuff ----------
  {
    const int b = bid >> 7;
    if (t < ND) sh.res.val[t] = wsI[OFF_VAL + b*ND + t];
    if (t >= 128 && t < 128 + NC) sh.res.cnt[t - 128] = wsI[OFF_COUNTS + b*32 + (t - 128)];
    __syncthreads();
    const int base = bid * 2048;
    #pragma unroll
    for (int i = 0; i < 8; ++i) {
      const int pid = base + i*256 + t;
      const int o = out[pid];
      int inst, cat;
      if (o < ND) {
        const int val = sh.res.val[o];
        inst = val & 0xffff;
        cat  = val >> 16;
      } else {
        inst = -1;
        const int cls = ((const unsigned char*)wsI)[OFF_SEGCLS*4 + pid];
        cat = (cls >= 2 && sh.res.cnt[cls] > 4096) ? cls + 90 : 0;
      }
      out[pid] = inst;
      out[NB*OH*OW + pid] = cat;
    }
  }
}

extern "C" void kernel_launch(void* const* d_in, const int* in_sizes, int n_in,
                              void* d_out, int out_size, void* d_ws, size_t ws_size,
                              hipStream_t stream) {
  const float* boxes   = (const float*)d_in[0];
  const int*   classes = (const int*)d_in[1];
  const float* scores  = (const float*)d_in[2];
  const float* dmasks  = (const float*)d_in[3];
  const float* segp    = (const float*)d_in[4];
  int* wsI = (int*)d_ws;
  int* out = (int*)d_out;

  hipMemsetAsync(wsI + OFF_COUNTS, 0, NB*32*sizeof(int), stream);   // class counters
  void* args[] = { (void*)&boxes, (void*)&classes, (void*)&scores, (void*)&dmasks,
                   (void*)&segp, (void*)&wsI, (void*)&out };
  hipLaunchCooperativeKernel((const void*)k_fused, dim3(256), dim3(256), args, 0, stream);
}

// Round 8
// 171.300 us; speedup vs baseline: 1.5419x; 1.5419x over previous
//
#include <hip/hip_runtime.h>

#pragma clang fp contract(off)

namespace {
constexpr int NB = 2, ND = 100, MH = 28, MW = 28;
constexpr int OH = 512, OW = 512;
constexpr int SH = 128, SW = 128, NC = 32;
constexpr int BMP_ROWS = 172;
constexpr int BMP8_ROWWORDS = 8;                        // canvas-aligned words per row
constexpr int BMP8_DETWORDS = BMP_ROWS * BMP8_ROWWORDS; // 1376

// workspace layout (int32 word indices)
constexpr int OFF_COUNTS = 0;                     // NB*32
constexpr int OFF_AREA   = 64;                    // NB*ND
constexpr int OFF_ACC    = OFF_AREA + NB*ND;
constexpr int OFF_YB     = OFF_ACC  + NB*ND;
constexpr int OFF_VAL    = OFF_YB   + NB*ND;
constexpr int OFF_QN     = OFF_VAL  + NB*ND;
constexpr int OFF_SEGCLS = OFF_QN   + NB*ND;      // byte region: NB*OH*OW bytes
constexpr int OFF_BMP8   = OFF_SEGCLS + (NB*OH*OW)/4;
constexpr int OCC_STRIDE = 25;                    // odd -> conflict-free; q0+7 <= 22 < 25
constexpr int OCC_WORDS  = OH * OCC_STRIDE;       // 12800 words = 51.2 KB
static_assert(OFF_BMP8 % 4 == 0, "uint4 alignment");

struct SegSh  { float patch[NC*342]; unsigned int h[NC]; };      // 43.9 KB
struct MaskSh { float sc[ND]; float sm[MH*MW]; int det; int area; };
union  K1Sh   { SegSh seg; MaskSh mask; };
}

// ---------------- seg tile: 64x64 out px, LDS-staged 18x18x32 patch (verified r7) ----------------
__device__ __forceinline__ void segTile(int tid, int t, const float* __restrict__ segp,
                                        int* __restrict__ wsI, int* __restrict__ out,
                                        SegSh& S) {
  const int b  = tid >> 6;
  const int tl = tid & 63;
  const int oy = (tl >> 3) * 64, ox = (tl & 7) * 64;
  const int iy0 = (oy >> 2) - 1, ix0 = (ox >> 2) - 1;
  if (t < NC) S.h[t] = 0u;
  // stage patch: 18x18 px x 8 float4
  for (int idx = t; idx < 18*18*8; idx += 256) {
    const int w  = idx & 7, px = idx >> 3;
    const int pr = px / 18, pc = px - pr*18;
    const int gy = min(max(iy0 + pr, 0), SH-1);
    const int gx = min(max(ix0 + pc, 0), SW-1);
    const float4 v = *(const float4*)(segp + (size_t)((b*SH + gy)*SW + gx)*NC + w*4);
    const int base = pr*19 + pc;
    S.patch[(w*4+0)*342 + base] = v.x;
    S.patch[(w*4+1)*342 + base] = v.y;
    S.patch[(w*4+2)*342 + base] = v.z;
    S.patch[(w*4+3)*342 + base] = v.w;
  }
  __syncthreads();
  const int ty2 = t >> 4, tx2 = t & 15;
  // per-output-row/col tables (weights exact eighths; clamp -> f=0 single-tap exact)
  int rlo[4], rhi[4], clo[4], chi[4];
  float fy[4], wy[4], fx[4], wx[4];
  #pragma unroll
  for (int u = 0; u < 4; ++u) {
    const int Y = oy + ty2*4 + u;
    float my = ((float)Y + 0.5f)*0.25f - 0.5f;
    float y0f = floorf(my);
    float f = my - y0f;
    int y0 = (int)y0f, y1 = y0 + 1;
    if (y0 < 0)           { y0 = 0; y1 = 0; f = 0.0f; }
    else if (y1 > SH - 1) { y1 = SH - 1; f = 0.0f; }
    rlo[u] = y0 - iy0; rhi[u] = y1 - iy0; fy[u] = f; wy[u] = 1.0f - f;
  }
  #pragma unroll
  for (int v = 0; v < 4; ++v) {
    const int X = ox + tx2*4 + v;
    float mx = ((float)X + 0.5f)*0.25f - 0.5f;
    float x0f = floorf(mx);
    float f = mx - x0f;
    int x0 = (int)x0f, x1 = x0 + 1;
    if (x0 < 0)           { x0 = 0; x1 = 0; f = 0.0f; }
    else if (x1 > SW - 1) { x1 = SW - 1; f = 0.0f; }
    clo[v] = x0 - ix0; chi[v] = x1 - ix0; fx[v] = f; wx[v] = 1.0f - f;
  }
  const int ro[4] = { rlo[0]*19, rhi[0]*19, rlo[2]*19, rhi[2]*19 };  // u01 pair, u23 pair
  const int co[4] = { clo[0],    chi[0],    clo[2],    chi[2]    };
  float best[4][4]; int bcls[4][4];
  #pragma unroll
  for (int u = 0; u < 4; ++u)
    #pragma unroll
    for (int v = 0; v < 4; ++v) { best[u][v] = -3.4e38f; bcls[u][v] = 0; }
  for (int ch = 0; ch < NC; ++ch) {
    const float* P = S.patch + ch*342;
    float tv[4][4];
    #pragma unroll
    for (int i = 0; i < 4; ++i)
      #pragma unroll
      for (int j = 0; j < 4; ++j)
        tv[i][j] = P[ro[i] + co[j]];
    float V[4][4];
    #pragma unroll
    for (int u = 0; u < 4; ++u) {
      const int lo = (u < 2) ? 0 : 2;
      #pragma unroll
      for (int j = 0; j < 4; ++j)
        V[u][j] = wy[u]*tv[lo][j] + fy[u]*tv[lo+1][j];   // vertical first (matches ref)
    }
    #pragma unroll
    for (int u = 0; u < 4; ++u)
      #pragma unroll
      for (int v = 0; v < 4; ++v) {
        const int lo = (v < 2) ? 0 : 2;
        float val = wx[v]*V[u][lo] + fx[v]*V[u][lo+1];
        if (val > best[u][v]) { best[u][v] = val; bcls[u][v] = ch; }  // strict > = first max
      }
  }
  unsigned int* segclsW = (unsigned int*)((char*)wsI + (size_t)OFF_SEGCLS*4);
  const uint4 sent = uint4{0x7FFFFFFFu,0x7FFFFFFFu,0x7FFFFFFFu,0x7FFFFFFFu};
  #pragma unroll
  for (int u = 0; u < 4; ++u) {
    const int Y = oy + ty2*4 + u, X = ox + tx2*4;
    const int pidw = (b*OH*OW + Y*OW + X) >> 2;
    segclsW[pidw] = (unsigned)bcls[u][0] | ((unsigned)bcls[u][1]<<8)
                  | ((unsigned)bcls[u][2]<<16) | ((unsigned)bcls[u][3]<<24);
    *(uint4*)(out + b*OH*OW + Y*OW + X) = sent;          // owner sentinel
    #pragma unroll
    for (int v = 0; v < 4; ++v)
      if (bcls[u][v] >= 2) atomicAdd(&S.h[bcls[u][v]], 1u);
  }
  __syncthreads();
  if (t < NC) {
    const unsigned int h = S.h[t];
    if (h) atomicAdd((unsigned int*)&wsI[OFF_COUNTS + b*32 + t], h);
  }
}

// ---------------- mask: per-det canvas-aligned bitmap + area (rank recomputed locally) ----------------
__device__ __forceinline__ void maskOne(int g, int t, const float* __restrict__ boxes,
                                        const int* __restrict__ classes,
                                        const float* __restrict__ scores,
                                        const float* __restrict__ dmasks,
                                        int* __restrict__ wsI, MaskSh& M) {
  const int b = g / ND, k = g - b*ND;
  if (t < ND) M.sc[t] = scores[b*ND + t];
  if (t == 0) M.area = 0;
  __syncthreads();
  if (t < ND) {
    float sn = M.sc[t];
    int r = 0;
    for (int j = 0; j < ND; ++j) {
      float sj = M.sc[j];
      r += (sj > sn) || (sj == sn && j < t);   // stable descending rank
    }
    if (r == k) M.det = t;
  }
  __syncthreads();
  const int det = M.det;
  const int cls = classes[b*ND + det];
  const float sc = M.sc[det];
  const float* bx = boxes + (size_t)(b*ND + det)*4;
  const float ymin = bx[0], xmin = bx[1], ymax = bx[2], xmax = bx[3];
  const bool keep = (sc > 0.5f) && (cls != 0);
  int ylo = (int)ceilf(ymin), yhi = (int)ceilf(ymax);
  int xlo = (int)ceilf(xmin), xhi = (int)ceilf(xmax);
  ylo = max(ylo, 0); xlo = max(xlo, 0);
  yhi = min(yhi, OH); xhi = min(xhi, OW);
  if (yhi < ylo) yhi = ylo;
  if (xhi < xlo) xhi = xlo;
  if (yhi - ylo > BMP_ROWS) yhi = ylo + BMP_ROWS;
  if (xhi - xlo > 192)      xhi = xlo + 192;
  const int yhi2 = keep ? yhi : ylo, xhi2 = keep ? xhi : xlo;
  const int rows = yhi2 - ylo, width = xhi2 - xlo;
  const int q0 = xlo >> 5;
  const int nw = (width > 0) ? (((xlo & 31) + width + 31) >> 5) : 0;
  if (t == 0) {
    wsI[OFF_YB  + g] = ylo | (yhi2 << 16);
    wsI[OFF_VAL + g] = (det + 1) | (cls << 16);
    wsI[OFF_QN  + g] = q0 | (nw << 16);
  }
  if (rows > 0 && width > 0) {               // uniform branch
    const float hs  = (ymax > ymin) ? (28.0f / (ymax - ymin)) : 0.0f;
    const float wsc = (xmax > xmin) ? (28.0f / (xmax - xmin)) : 0.0f;
    const float* mp = dmasks + (size_t)(b*ND + det)*(MH*MW);
    for (int i = t; i < MH*MW; i += 256) M.sm[i] = mp[i];
    __syncthreads();
    unsigned int* bmp8 = (unsigned int*)wsI + OFF_BMP8 + g*BMP8_DETWORDS;
    const int iw = t >> 5, bit = t & 31;
    const int x = ((q0 + iw) << 5) + bit;
    const bool inbox = (x >= xlo) && (x < xhi2);
    for (int r = 0; r < rows; ++r) {
      const int y = ylo + r;
      bool pred = false;
      if (inbox) {
        // exact op order of _paste_one (fp contract off)
        float ty = ((float)y + 0.5f); ty = ty - ymin; ty = ty * hs;  float my = ty - 0.5f;
        float tx = ((float)x + 0.5f); tx = tx - xmin; tx = tx * wsc; float mx = tx - 0.5f;
        float y0f = floorf(my), x0f = floorf(mx);
        float ly = my - y0f, lx = mx - x0f;
        int y0 = (int)y0f, x0 = (int)x0f;
        int y1 = min(max(y0 + 1, 0), MH - 1);
        int x1 = min(max(x0 + 1, 0), MW - 1);
        y0 = min(max(y0, 0), MH - 1);
        x0 = min(max(x0, 0), MW - 1);
        float v00 = M.sm[y0*MW + x0], v01 = M.sm[y0*MW + x1];
        float v10 = M.sm[y1*MW + x0], v11 = M.sm[y1*MW + x1];
        float omlx = 1.0f - lx, omly = 1.0f - ly;
        float top = omlx*v00 + lx*v01;
        float bot = omlx*v10 + lx*v11;
        float outv = omly*top + ly*bot;
        pred = outv > 0.5f;
      }
      unsigned long long m = __ballot(pred);
      unsigned int word = (t & 32) ? (unsigned int)(m >> 32) : (unsigned int)m;
      if (bit == 0) {
        bmp8[r*BMP8_ROWWORDS + iw] = word;
        if (word) atomicAdd(&M.area, __popc(word));
      }
    }
  }
  __syncthreads();
  if (t == 0) wsI[OFF_AREA + g] = (rows > 0 && width > 0) ? M.area : 0;
}

// ================= K1: tiled seg (blocks 0..127) + masks (blocks 128..327) =================
__global__ void __launch_bounds__(256) k_segmask(
    const float* __restrict__ boxes, const int* __restrict__ classes,
    const float* __restrict__ scores, const float* __restrict__ dmasks,
    const float* __restrict__ segp, int* __restrict__ wsI, int* __restrict__ out) {
  __shared__ K1Sh sh;
  const int bid = blockIdx.x, t = threadIdx.x;
  if (bid < 128) segTile(bid, t, segp, wsI, out, sh.seg);
  else           maskOne(bid - 128, t, boxes, classes, scores, dmasks, wsI, sh.mask);
}

// ================= K2: scan -> accept flags (1 wave/block, no spills) =================
__device__ __forceinline__ void loadDet(const uint4* __restrict__ base, int g, int t,
                                        int rows, bool wide, uint4 lo[3], uint4 hi[3]) {
  const uint4* p = base + (size_t)g*(BMP8_DETWORDS/4);
  #pragma unroll
  for (int j = 0; j < 3; ++j) {
    const int rr = t + j*64;
    lo[j] = uint4{0,0,0,0}; hi[j] = uint4{0,0,0,0};
    if (rr < rows) {
      lo[j] = p[rr*2 + 0];
      if (wide) hi[j] = p[rr*2 + 1];       // wave-uniform branch
    }
  }
}

template<int NW>   // uint4s per row actually carrying bits (1 or 2)
__device__ __forceinline__ void processDet(int t, const uint4 lo[3], const uint4 hi[3],
                                           unsigned int* occ, int area, int yb, int q0,
                                           int* __restrict__ accp) {
  constexpr int W = NW*4;
  const int ylo = yb & 0xffff;
  const int rows = (yb >> 16) - ylo;
  unsigned int w[3][W], o[3][W];
  int rb_[3];
  int cnt = 0;
  #pragma unroll
  for (int j = 0; j < 3; ++j) {
    const int rr = t + j*64;
    if (rr < rows) {                       // exec-masked; dead quarters skip LDS entirely
      const int rb = (ylo + rr) * OCC_STRIDE + q0;
      rb_[j] = rb;
      w[j][0] = lo[j].x; w[j][1] = lo[j].y; w[j][2] = lo[j].z; w[j][3] = lo[j].w;
      if (NW == 2) { w[j][4] = hi[j].x; w[j][5] = hi[j].y; w[j][6] = hi[j].z; w[j][7] = hi[j].w; }
      #pragma unroll
      for (int i = 0; i < W; ++i) {
        const unsigned int ov = occ[rb + i];
        cnt += __popc(w[j][i] & ov);
        o[j][i] = ov;
      }
    }
  }
  #pragma unroll
  for (int off = 32; off; off >>= 1) cnt += __shfl_xor(cnt, off);
  const bool acc = ((float)cnt / (float)area) < 0.5f;   // area>=1 (compacted list)
  if (acc) {
    if (t == 0) *accp = 1;
    #pragma unroll
    for (int j = 0; j < 3; ++j) {
      if (t + j*64 < rows) {
        #pragma unroll
        for (int i = 0; i < W; ++i) occ[rb_[j] + i] = o[j][i] | w[j][i];
      }
    }
  }
}

__global__ void __launch_bounds__(64) k_scan(int* __restrict__ wsI) {
  const int b = blockIdx.x, t = threadIdx.x;   // 1 wave, lockstep
  __shared__ unsigned int occ[OCC_WORDS];      // 51.2 KB
  __shared__ int s_list[ND], s_area[ND], s_yb[ND], s_q0[ND], s_nw[ND];
  for (int i = t; i < OCC_WORDS; i += 64) occ[i] = 0u;
  for (int i = t; i < ND; i += 64) {
    s_area[i] = wsI[OFF_AREA + b*ND + i];
    s_yb[i]   = wsI[OFF_YB   + b*ND + i];
    const int qn = wsI[OFF_QN + b*ND + i];
    s_q0[i] = qn & 0xffff;
    s_nw[i] = qn >> 16;
    wsI[OFF_ACC + b*ND + i] = 0;
  }
  __syncthreads();
  int nact = 0;                                 // ordered compaction of area>0 dets
  for (int base = 0; base < ND; base += 64) {
    const int i = base + t;
    const bool a = (i < ND) && (s_area[i] > 0);
    unsigned long long m = __ballot(a);
    int pos = nact + __popcll(m & ((1ull << t) - 1ull));
    if (a) s_list[pos] = i;
    nact += (int)__popcll(m);
  }
  __syncthreads();
  if (nact == 0) return;
  const uint4* bmp4 = (const uint4*)((unsigned int*)wsI + OFF_BMP8 + (size_t)b*ND*BMP8_DETWORDS);
  int* accB = wsI + OFF_ACC + b*ND;
  uint4 Alo[3], Ahi[3], Blo[3], Bhi[3], Clo[3], Chi[3];
  const int last = nact - 1;
  auto rowsOf = [&](int g) { return (s_yb[g] >> 16) - (s_yb[g] & 0xffff); };
  {
    const int g0 = s_list[0], g1 = s_list[min(1, last)];
    loadDet(bmp4, g0, t, rowsOf(g0), s_nw[g0] > 4, Alo, Ahi);
    loadDet(bmp4, g1, t, rowsOf(g1), s_nw[g1] > 4, Blo, Bhi);
  }
  for (int ii = 0; ii < nact; ii += 3) {
    const int gC = s_list[min(ii+2, last)];
    loadDet(bmp4, gC, t, rowsOf(gC), s_nw[gC] > 4, Clo, Chi);
    { const int g = s_list[ii];
      if (s_nw[g] > 4) processDet<2>(t, Alo, Ahi, occ, s_area[g], s_yb[g], s_q0[g], accB + g);
      else             processDet<1>(t, Alo, Ahi, occ, s_area[g], s_yb[g], s_q0[g], accB + g); }
    const int gA = s_list[min(ii+3, last)];
    loadDet(bmp4, gA, t, rowsOf(gA), s_nw[gA] > 4, Alo, Ahi);
    if (ii+1 < nact) { const int g = s_list[ii+1];
      if (s_nw[g] > 4) processDet<2>(t, Blo, Bhi, occ, s_area[g], s_yb[g], s_q0[g], accB + g);
      else             processDet<1>(t, Blo, Bhi, occ, s_area[g], s_yb[g], s_q0[g], accB + g); }
    const int gB = s_list[min(ii+4, last)];
    loadDet(bmp4, gB, t, rowsOf(gB), s_nw[gB] > 4, Blo, Bhi);
    if (ii+2 < nact) { const int g = s_list[ii+2];
      if (s_nw[g] > 4) processDet<2>(t, Clo, Chi, occ, s_area[g], s_yb[g], s_q0[g], accB + g);
      else             processDet<1>(t, Clo, Chi, occ, s_area[g], s_yb[g], s_q0[g], accB + g); }
  }
}

// ================= K3: paint owners via atomicMin over bitmaps =================
__global__ void k_paint(const int* __restrict__ wsI, int* __restrict__ out) {
  const int g = blockIdx.x;             // b*ND + k
  if (!wsI[OFF_ACC + g]) return;        // uniform
  const int t = threadIdx.x;            // 256 = 8 words x 32 bits
  const int b = g / ND, k = g - b*ND;
  const int yb = wsI[OFF_YB + g];
  const int ylo = yb & 0xffff;
  const int rows = (yb >> 16) - ylo;
  const int q0 = wsI[OFF_QN + g] & 0xffff;
  const unsigned int* bmp = (const unsigned int*)wsI + OFF_BMP8 + g*BMP8_DETWORDS;
  int* __restrict__ owner = out + b*(OH*OW);     // plane 0 doubles as owner map
  const int iw = t >> 5, bit = t & 31;
  const int x = ((q0 + iw) << 5) + bit;
  if (x >= OW) return;                  // pad-word lanes: bits are provably zero
  for (int r = 0; r < rows; ++r) {
    const unsigned int wv = bmp[r*BMP8_ROWWORDS + iw];
    if ((wv >> bit) & 1u)
      atomicMin(&owner[(ylo + r)*OW + x], k);    // owner = min sorted rank == ref
  }
}

// ================= K4: resolve owner -> inst/cat, else stuff =================
__global__ void k_resolve(const int* __restrict__ wsI, int* __restrict__ out) {
  const int t = threadIdx.x;
  const int pid = blockIdx.x*256 + t;
  const int b = pid >> 18;
  __shared__ int s_val[ND];
  __shared__ int s_cnt[NC];
  if (t < ND) s_val[t] = wsI[OFF_VAL + b*ND + t];
  if (t >= 128 && t < 128 + NC) s_cnt[t - 128] = wsI[OFF_COUNTS + b*32 + (t - 128)];
  __syncthreads();
  const int o = out[pid];                // owner (sorted rank) or sentinel
  int inst, cat;
  if (o < ND) {
    const int val = s_val[o];
    inst = val & 0xffff;
    cat  = val >> 16;
  } else {
    inst = -1;
    const int cls = ((const unsigned char*)wsI)[OFF_SEGCLS*4 + pid];
    cat = (cls >= 2 && s_cnt[cls] > 4096) ? cls + 90 : 0;
  }
  out[pid] = inst;
  out[NB*OH*OW + pid] = cat;
}

extern "C" void kernel_launch(void* const* d_in, const int* in_sizes, int n_in,
                              void* d_out, int out_size, void* d_ws, size_t ws_size,
                              hipStream_t stream) {
  const float* boxes   = (const float*)d_in[0];
  const int*   classes = (const int*)d_in[1];
  const float* scores  = (const float*)d_in[2];
  const float* dmasks  = (const float*)d_in[3];
  const float* segp    = (const float*)d_in[4];
  int* wsI = (int*)d_ws;
  int* out = (int*)d_out;

  hipMemsetAsync(wsI + OFF_COUNTS, 0, NB*32*sizeof(int), stream);   // class counters
  k_segmask<<<128 + NB*ND, 256, 0, stream>>>(boxes, classes, scores, dmasks, segp, wsI, out);
  k_scan   <<<NB, 64, 0, stream>>>(wsI);
  k_paint  <<<NB*ND, 256, 0, stream>>>(wsI, out);
  k_resolve<<<(NB*OH*OW)/256, 256, 0, stream>>>(wsI, out);
}

// Round 9
// 158.686 us; speedup vs baseline: 1.6645x; 1.0795x over previous
//
#include <hip/hip_runtime.h>

#pragma clang fp contract(off)

namespace {
constexpr int NB = 2, ND = 100, MH = 28, MW = 28;
constexpr int OH = 512, OW = 512;
constexpr int SH = 128, SW = 128, NC = 32;
constexpr int BMP_ROWS = 172;
constexpr int BMP8_ROWWORDS = 8;                        // canvas-aligned words per row
constexpr int BMP8_DETWORDS = BMP_ROWS * BMP8_ROWWORDS; // 1376

// workspace layout (int32 word indices)
constexpr int OFF_COUNTS = 0;                     // NB*32
constexpr int OFF_AREA   = 64;                    // NB*ND
constexpr int OFF_ACC    = OFF_AREA + NB*ND;
constexpr int OFF_YB     = OFF_ACC  + NB*ND;
constexpr int OFF_VAL    = OFF_YB   + NB*ND;
constexpr int OFF_QN     = OFF_VAL  + NB*ND;
constexpr int OFF_SEGCLS = OFF_QN   + NB*ND;      // byte region: NB*OH*OW bytes
constexpr int OFF_BMP8   = OFF_SEGCLS + (NB*OH*OW)/4;
constexpr int OCC_STRIDE = 25;                    // odd -> conflict-free; q0+7 <= 22 < 25
constexpr int OCC_WORDS  = OH * OCC_STRIDE;       // 12800 words = 51.2 KB
constexpr int SEGW_TOTAL = (NB*OH*OW)/4;          // 131072 segcls words
constexpr int SEGW_PER_PAINT = (SEGW_TOTAL + NB*ND - 1)/(NB*ND);   // 656
static_assert(OFF_BMP8 % 4 == 0, "uint4 alignment");

struct SegSh  { float patch[NC*342]; };                          // 43.8 KB
struct MaskSh { float sc[ND]; float sm[MH*MW]; int det; int area; };
union  K1Sh   { SegSh seg; MaskSh mask; };
}

// ---------------- seg tile: 64x64 out px, LDS-staged 18x18x32 patch (verified r7/r8) ----------------
__device__ __forceinline__ void segTile(int tid, int t, const float* __restrict__ segp,
                                        int* __restrict__ wsI, int* __restrict__ out,
                                        SegSh& S) {
  const int b  = tid >> 6;
  const int tl = tid & 63;
  const int oy = (tl >> 3) * 64, ox = (tl & 7) * 64;
  const int iy0 = (oy >> 2) - 1, ix0 = (ox >> 2) - 1;
  // stage patch: 18x18 px x 8 float4
  for (int idx = t; idx < 18*18*8; idx += 256) {
    const int w  = idx & 7, px = idx >> 3;
    const int pr = px / 18, pc = px - pr*18;
    const int gy = min(max(iy0 + pr, 0), SH-1);
    const int gx = min(max(ix0 + pc, 0), SW-1);
    const float4 v = *(const float4*)(segp + (size_t)((b*SH + gy)*SW + gx)*NC + w*4);
    const int base = pr*19 + pc;
    S.patch[(w*4+0)*342 + base] = v.x;
    S.patch[(w*4+1)*342 + base] = v.y;
    S.patch[(w*4+2)*342 + base] = v.z;
    S.patch[(w*4+3)*342 + base] = v.w;
  }
  __syncthreads();
  const int ty2 = t >> 4, tx2 = t & 15;
  int rlo[4], rhi[4], clo[4], chi[4];
  float fy[4], wy[4], fx[4], wx[4];
  #pragma unroll
  for (int u = 0; u < 4; ++u) {
    const int Y = oy + ty2*4 + u;
    float my = ((float)Y + 0.5f)*0.25f - 0.5f;
    float y0f = floorf(my);
    float f = my - y0f;
    int y0 = (int)y0f, y1 = y0 + 1;
    if (y0 < 0)           { y0 = 0; y1 = 0; f = 0.0f; }
    else if (y1 > SH - 1) { y1 = SH - 1; f = 0.0f; }
    rlo[u] = y0 - iy0; rhi[u] = y1 - iy0; fy[u] = f; wy[u] = 1.0f - f;
  }
  #pragma unroll
  for (int v = 0; v < 4; ++v) {
    const int X = ox + tx2*4 + v;
    float mx = ((float)X + 0.5f)*0.25f - 0.5f;
    float x0f = floorf(mx);
    float f = mx - x0f;
    int x0 = (int)x0f, x1 = x0 + 1;
    if (x0 < 0)           { x0 = 0; x1 = 0; f = 0.0f; }
    else if (x1 > SW - 1) { x1 = SW - 1; f = 0.0f; }
    clo[v] = x0 - ix0; chi[v] = x1 - ix0; fx[v] = f; wx[v] = 1.0f - f;
  }
  const int ro[4] = { rlo[0]*19, rhi[0]*19, rlo[2]*19, rhi[2]*19 };
  const int co[4] = { clo[0],    chi[0],    clo[2],    chi[2]    };
  float best[4][4]; int bcls[4][4];
  #pragma unroll
  for (int u = 0; u < 4; ++u)
    #pragma unroll
    for (int v = 0; v < 4; ++v) { best[u][v] = -3.4e38f; bcls[u][v] = 0; }
  for (int ch = 0; ch < NC; ++ch) {
    const float* P = S.patch + ch*342;
    float tv[4][4];
    #pragma unroll
    for (int i = 0; i < 4; ++i)
      #pragma unroll
      for (int j = 0; j < 4; ++j)
        tv[i][j] = P[ro[i] + co[j]];
    float V[4][4];
    #pragma unroll
    for (int u = 0; u < 4; ++u) {
      const int lo = (u < 2) ? 0 : 2;
      #pragma unroll
      for (int j = 0; j < 4; ++j)
        V[u][j] = wy[u]*tv[lo][j] + fy[u]*tv[lo+1][j];   // vertical first (matches ref)
    }
    #pragma unroll
    for (int u = 0; u < 4; ++u)
      #pragma unroll
      for (int v = 0; v < 4; ++v) {
        const int lo = (v < 2) ? 0 : 2;
        float val = wx[v]*V[u][lo] + fx[v]*V[u][lo+1];
        if (val > best[u][v]) { best[u][v] = val; bcls[u][v] = ch; }  // strict > = first max
      }
  }
  unsigned int* segclsW = (unsigned int*)((char*)wsI + (size_t)OFF_SEGCLS*4);
  const uint4 sent = uint4{0x7FFFFFFFu,0x7FFFFFFFu,0x7FFFFFFFu,0x7FFFFFFFu};
  #pragma unroll
  for (int u = 0; u < 4; ++u) {
    const int Y = oy + ty2*4 + u, X = ox + tx2*4;
    const int pidw = (b*OH*OW + Y*OW + X) >> 2;
    segclsW[pidw] = (unsigned)bcls[u][0] | ((unsigned)bcls[u][1]<<8)
                  | ((unsigned)bcls[u][2]<<16) | ((unsigned)bcls[u][3]<<24);
    *(uint4*)(out + b*OH*OW + Y*OW + X) = sent;          // owner sentinel
  }
}

// ---------------- mask: per-det canvas-aligned bitmap + area (verified r5-r8) ----------------
__device__ __forceinline__ void maskOne(int g, int t, const float* __restrict__ boxes,
                                        const int* __restrict__ classes,
                                        const float* __restrict__ scores,
                                        const float* __restrict__ dmasks,
                                        int* __restrict__ wsI, MaskSh& M) {
  const int b = g / ND, k = g - b*ND;
  if (t < ND) M.sc[t] = scores[b*ND + t];
  if (t == 0) M.area = 0;
  __syncthreads();
  if (t < ND) {
    float sn = M.sc[t];
    int r = 0;
    for (int j = 0; j < ND; ++j) {
      float sj = M.sc[j];
      r += (sj > sn) || (sj == sn && j < t);   // stable descending rank
    }
    if (r == k) M.det = t;
  }
  __syncthreads();
  const int det = M.det;
  const int cls = classes[b*ND + det];
  const float sc = M.sc[det];
  const float* bx = boxes + (size_t)(b*ND + det)*4;
  const float ymin = bx[0], xmin = bx[1], ymax = bx[2], xmax = bx[3];
  const bool keep = (sc > 0.5f) && (cls != 0);
  int ylo = (int)ceilf(ymin), yhi = (int)ceilf(ymax);
  int xlo = (int)ceilf(xmin), xhi = (int)ceilf(xmax);
  ylo = max(ylo, 0); xlo = max(xlo, 0);
  yhi = min(yhi, OH); xhi = min(xhi, OW);
  if (yhi < ylo) yhi = ylo;
  if (xhi < xlo) xhi = xlo;
  if (yhi - ylo > BMP_ROWS) yhi = ylo + BMP_ROWS;
  if (xhi - xlo > 192)      xhi = xlo + 192;
  const int yhi2 = keep ? yhi : ylo, xhi2 = keep ? xhi : xlo;
  const int rows = yhi2 - ylo, width = xhi2 - xlo;
  const int q0 = xlo >> 5;
  const int nw = (width > 0) ? (((xlo & 31) + width + 31) >> 5) : 0;
  if (t == 0) {
    wsI[OFF_YB  + g] = ylo | (yhi2 << 16);
    wsI[OFF_VAL + g] = (det + 1) | (cls << 16);
    wsI[OFF_QN  + g] = q0 | (nw << 16);
  }
  if (rows > 0 && width > 0) {
    const float hs  = (ymax > ymin) ? (28.0f / (ymax - ymin)) : 0.0f;
    const float wsc = (xmax > xmin) ? (28.0f / (xmax - xmin)) : 0.0f;
    const float* mp = dmasks + (size_t)(b*ND + det)*(MH*MW);
    for (int i = t; i < MH*MW; i += 256) M.sm[i] = mp[i];
    __syncthreads();
    unsigned int* bmp8 = (unsigned int*)wsI + OFF_BMP8 + g*BMP8_DETWORDS;
    const int iw = t >> 5, bit = t & 31;
    const int x = ((q0 + iw) << 5) + bit;
    const bool inbox = (x >= xlo) && (x < xhi2);
    for (int r = 0; r < rows; ++r) {
      const int y = ylo + r;
      bool pred = false;
      if (inbox) {
        // exact op order of _paste_one (fp contract off)
        float ty = ((float)y + 0.5f); ty = ty - ymin; ty = ty * hs;  float my = ty - 0.5f;
        float tx = ((float)x + 0.5f); tx = tx - xmin; tx = tx * wsc; float mx = tx - 0.5f;
        float y0f = floorf(my), x0f = floorf(mx);
        float ly = my - y0f, lx = mx - x0f;
        int y0 = (int)y0f, x0 = (int)x0f;
        int y1 = min(max(y0 + 1, 0), MH - 1);
        int x1 = min(max(x0 + 1, 0), MW - 1);
        y0 = min(max(y0, 0), MH - 1);
        x0 = min(max(x0, 0), MW - 1);
        float v00 = M.sm[y0*MW + x0], v01 = M.sm[y0*MW + x1];
        float v10 = M.sm[y1*MW + x0], v11 = M.sm[y1*MW + x1];
        float omlx = 1.0f - lx, omly = 1.0f - ly;
        float top = omlx*v00 + lx*v01;
        float bot = omlx*v10 + lx*v11;
        float outv = omly*top + ly*bot;
        pred = outv > 0.5f;
      }
      unsigned long long m = __ballot(pred);
      unsigned int word = (t & 32) ? (unsigned int)(m >> 32) : (unsigned int)m;
      if (bit == 0) {
        bmp8[r*BMP8_ROWWORDS + iw] = word;
        if (word) atomicAdd(&M.area, __popc(word));
      }
    }
  }
  __syncthreads();
  if (t == 0) wsI[OFF_AREA + g] = (rows > 0 && width > 0) ? M.area : 0;
}

// ================= K1: tiled seg (blocks 0..127) + masks (blocks 128..327) =================
__global__ void __launch_bounds__(256) k_segmask(
    const float* __restrict__ boxes, const int* __restrict__ classes,
    const float* __restrict__ scores, const float* __restrict__ dmasks,
    const float* __restrict__ segp, int* __restrict__ wsI, int* __restrict__ out) {
  __shared__ K1Sh sh;
  const int bid = blockIdx.x, t = threadIdx.x;
  if (bid < 128) segTile(bid, t, segp, wsI, out, sh.seg);
  else           maskOne(bid - 128, t, boxes, classes, scores, dmasks, wsI, sh.mask);
}

// ================= K2: scan -> accept flags (1 wave/batch, DPP reduce) =================
namespace {
struct DetReg {
  int gIdx, yb, q0, thr;
  uint4 lo0, hi0, lo1, hi1, lo2, hi2;
};
}

__device__ __forceinline__ void fetchDet(const uint4* __restrict__ bmp4,
                                         const int* s_yb, const int* s_q0, const int* s_thr,
                                         int g, int t, DetReg& D) {
  D.gIdx = g;
  D.yb  = s_yb[g];
  D.q0  = s_q0[g];
  D.thr = s_thr[g];
  const int rows = (D.yb >> 16) - (D.yb & 0xffff);
  const uint4* p = bmp4 + (size_t)g*(BMP8_DETWORDS/4);
  const uint4 z = uint4{0,0,0,0};
  D.lo0 = z; D.hi0 = z; D.lo1 = z; D.hi1 = z; D.lo2 = z; D.hi2 = z;
  if (t < rows)         { D.lo0 = p[t*2];         D.hi0 = p[t*2 + 1]; }
  if (t + 64 < rows)    { D.lo1 = p[(t+64)*2];    D.hi1 = p[(t+64)*2 + 1]; }
  if (t + 128 < rows)   { D.lo2 = p[(t+128)*2];   D.hi2 = p[(t+128)*2 + 1]; }
}

__device__ __forceinline__ int quarterCount(const uint4& lo, const uint4& hi, bool valid,
                                            int rb, const unsigned int* occ,
                                            unsigned int o[8]) {
  int c = 0;
  if (valid) {
    o[0] = occ[rb+0]; o[1] = occ[rb+1]; o[2] = occ[rb+2]; o[3] = occ[rb+3];
    o[4] = occ[rb+4]; o[5] = occ[rb+5]; o[6] = occ[rb+6]; o[7] = occ[rb+7];
    c += __popc(lo.x & o[0]); c += __popc(lo.y & o[1]);
    c += __popc(lo.z & o[2]); c += __popc(lo.w & o[3]);
    c += __popc(hi.x & o[4]); c += __popc(hi.y & o[5]);
    c += __popc(hi.z & o[6]); c += __popc(hi.w & o[7]);
  }
  return c;
}

__device__ __forceinline__ void quarterWrite(const uint4& lo, const uint4& hi, bool valid,
                                             int rb, unsigned int* occ,
                                             const unsigned int o[8]) {
  if (valid) {
    occ[rb+0] = o[0] | lo.x; occ[rb+1] = o[1] | lo.y;
    occ[rb+2] = o[2] | lo.z; occ[rb+3] = o[3] | lo.w;
    occ[rb+4] = o[4] | hi.x; occ[rb+5] = o[5] | hi.y;
    occ[rb+6] = o[6] | hi.z; occ[rb+7] = o[7] | hi.w;
  }
}

__device__ __forceinline__ void processDet(int t, const DetReg& D, unsigned int* occ,
                                           int* __restrict__ accB) {
  const int ylo = D.yb & 0xffff;
  const int rows = (D.yb >> 16) - ylo;
  const bool v0 = t < rows, v1 = t + 64 < rows, v2 = t + 128 < rows;
  const int rb0 = (ylo + t) * OCC_STRIDE + D.q0;
  const int rb1 = rb0 + 64*OCC_STRIDE;
  const int rb2 = rb0 + 128*OCC_STRIDE;
  unsigned int o0[8], o1[8], o2[8];
  int cnt = quarterCount(D.lo0, D.hi0, v0, rb0, occ, o0)
          + quarterCount(D.lo1, D.hi1, v1, rb1, occ, o1)
          + quarterCount(D.lo2, D.hi2, v2, rb2, occ, o2);
  // 64-lane sum via DPP (row_shr 1/2/4/8 + row_bcast15/31), total lands in lane 63
  cnt += __builtin_amdgcn_update_dpp(0, cnt, 0x111, 0xF, 0xF, false);
  cnt += __builtin_amdgcn_update_dpp(0, cnt, 0x112, 0xF, 0xF, false);
  cnt += __builtin_amdgcn_update_dpp(0, cnt, 0x114, 0xF, 0xF, false);
  cnt += __builtin_amdgcn_update_dpp(0, cnt, 0x118, 0xF, 0xF, false);
  cnt += __builtin_amdgcn_update_dpp(0, cnt, 0x142, 0xF, 0xF, false);
  cnt += __builtin_amdgcn_update_dpp(0, cnt, 0x143, 0xF, 0xF, false);
  const int total = __builtin_amdgcn_readlane(cnt, 63);
  if (total < D.thr) {                       // == (float)total/area < 0.5f, by construction
    if (t == 0) accB[D.gIdx] = 1;
    quarterWrite(D.lo0, D.hi0, v0, rb0, occ, o0);
    quarterWrite(D.lo1, D.hi1, v1, rb1, occ, o1);
    quarterWrite(D.lo2, D.hi2, v2, rb2, occ, o2);
  }
}

__global__ void __launch_bounds__(64) k_scan(int* __restrict__ wsI) {
  const int bid = blockIdx.x, t = threadIdx.x;
  if (bid >= NB) {                           // spare blocks: zero class counters for k_paint
    if (t < 32) wsI[OFF_COUNTS + (bid - NB)*32 + t] = 0;
    return;
  }
  const int b = bid;                          // 1 wave, lockstep, barrier-free main loop
  __shared__ unsigned int occ[OCC_WORDS];     // 51.2 KB
  __shared__ int s_list[ND], s_area[ND], s_yb[ND], s_q0[ND], s_thr[ND];
  for (int i = t; i < OCC_WORDS; i += 64) occ[i] = 0u;
  for (int i = t; i < ND; i += 64) {
    const int area = wsI[OFF_AREA + b*ND + i];
    s_area[i] = area;
    s_yb[i]   = wsI[OFF_YB + b*ND + i];
    s_q0[i]   = wsI[OFF_QN + b*ND + i] & 0xffff;
    int c = 0;
    if (area > 0) {                           // min c with (float)c/area >= 0.5f
      const float a = (float)area;
      c = (area + 1) >> 1;
      while (c > 0 && (float)(c - 1) / a >= 0.5f) --c;
      while ((float)c / a < 0.5f) ++c;
    }
    s_thr[i] = c;
    wsI[OFF_ACC + b*ND + i] = 0;
  }
  __syncthreads();
  int nact = 0;                               // ordered compaction of area>0 dets
  for (int base = 0; base < ND; base += 64) {
    const int i = base + t;
    const bool a = (i < ND) && (s_area[i] > 0);
    unsigned long long m = __ballot(a);
    int pos = nact + __popcll(m & ((1ull << t) - 1ull));
    if (a) s_list[pos] = i;
    nact += (int)__popcll(m);
  }
  __syncthreads();
  if (nact == 0) return;
  const uint4* bmp4 = (const uint4*)((unsigned int*)wsI + OFF_BMP8 + (size_t)b*ND*BMP8_DETWORDS);
  int* accB = wsI + OFF_ACC + b*ND;
  const int last = nact - 1;
  DetReg A, B, C;
  fetchDet(bmp4, s_yb, s_q0, s_thr, s_list[0], t, A);
  fetchDet(bmp4, s_yb, s_q0, s_thr, s_list[min(1, last)], t, B);
  for (int ii = 0; ii < nact; ii += 3) {
    fetchDet(bmp4, s_yb, s_q0, s_thr, s_list[min(ii+2, last)], t, C);
    processDet(t, A, occ, accB);
    fetchDet(bmp4, s_yb, s_q0, s_thr, s_list[min(ii+3, last)], t, A);
    if (ii+1 < nact) processDet(t, B, occ, accB);
    fetchDet(bmp4, s_yb, s_q0, s_thr, s_list[min(ii+4, last)], t, B);
    if (ii+2 < nact) processDet(t, C, occ, accB);
  }
}

// ================= K3: stuff histogram slice + paint owners via atomicMin =================
__global__ void k_paint(int* __restrict__ wsI, int* __restrict__ out) {
  const int g = blockIdx.x;             // b*ND + k
  const int t = threadIdx.x;            // 256
  // --- histogram slice (every block) ---
  __shared__ unsigned int h[2*NC];
  if (t < 2*NC) h[t] = 0u;
  __syncthreads();
  const unsigned int* segclsW = (const unsigned int*)((const char*)wsI + (size_t)OFF_SEGCLS*4);
  const int w0 = g * SEGW_PER_PAINT;
  const int w1 = min(w0 + SEGW_PER_PAINT, SEGW_TOTAL);
  for (int wi = w0 + t; wi < w1; wi += 256) {
    const unsigned int w = segclsW[wi];
    const int hb = (wi >> 16) << 5;     // b*32
    #pragma unroll
    for (int by = 0; by < 4; ++by) {
      const int cls = (w >> (by*8)) & 0xff;
      if (cls >= 2) atomicAdd(&h[hb + cls], 1u);
    }
  }
  __syncthreads();
  if (t < 2*NC) {
    const unsigned int v = h[t];
    if (v) atomicAdd((unsigned int*)&wsI[OFF_COUNTS + t], v);
  }
  // --- paint (accepted dets only) ---
  if (!wsI[OFF_ACC + g]) return;        // uniform
  const int b = g / ND, k = g - b*ND;
  const int yb = wsI[OFF_YB + g];
  const int ylo = yb & 0xffff;
  const int rows = (yb >> 16) - ylo;
  const int q0 = wsI[OFF_QN + g] & 0xffff;
  const unsigned int* bmp = (const unsigned int*)wsI + OFF_BMP8 + g*BMP8_DETWORDS;
  int* __restrict__ owner = out + b*(OH*OW);     // plane 0 doubles as owner map
  const int iw = t >> 5, bit = t & 31;
  const int x = ((q0 + iw) << 5) + bit;
  if (x >= OW) return;                  // pad-word lanes carry zero bits
  for (int r = 0; r < rows; ++r) {
    const unsigned int wv = bmp[r*BMP8_ROWWORDS + iw];
    if ((wv >> bit) & 1u)
      atomicMin(&owner[(ylo + r)*OW + x], k);    // owner = min sorted rank == ref
  }
}

// ================= K4: resolve owner -> inst/cat, else stuff (uint4 vectorized) =================
__global__ void k_resolve(const int* __restrict__ wsI, int* __restrict__ out) {
  const int t = threadIdx.x;
  const int q = blockIdx.x*256 + t;      // quad index (4 px)
  const int b = q >> 16;
  __shared__ int s_val[ND];
  __shared__ int s_cnt[NC];
  if (t < ND) s_val[t] = wsI[OFF_VAL + b*ND + t];
  if (t >= 128 && t < 128 + NC) s_cnt[t - 128] = wsI[OFF_COUNTS + b*32 + (t - 128)];
  __syncthreads();
  const uint4 o4 = ((const uint4*)out)[q];
  const unsigned int clsw = ((const unsigned int*)((const char*)wsI + (size_t)OFF_SEGCLS*4))[q];
  uint4 i4, c4;
  {
    const int o = (int)o4.x;
    if (o < ND) { const int v = s_val[o]; i4.x = v & 0xffff; c4.x = v >> 16; }
    else { i4.x = (unsigned)-1; const int cl = clsw & 0xff;
           c4.x = (cl >= 2 && s_cnt[cl] > 4096) ? cl + 90 : 0; }
  }
  {
    const int o = (int)o4.y;
    if (o < ND) { const int v = s_val[o]; i4.y = v & 0xffff; c4.y = v >> 16; }
    else { i4.y = (unsigned)-1; const int cl = (clsw >> 8) & 0xff;
           c4.y = (cl >= 2 && s_cnt[cl] > 4096) ? cl + 90 : 0; }
  }
  {
    const int o = (int)o4.z;
    if (o < ND) { const int v = s_val[o]; i4.z = v & 0xffff; c4.z = v >> 16; }
    else { i4.z = (unsigned)-1; const int cl = (clsw >> 16) & 0xff;
           c4.z = (cl >= 2 && s_cnt[cl] > 4096) ? cl + 90 : 0; }
  }
  {
    const int o = (int)o4.w;
    if (o < ND) { const int v = s_val[o]; i4.w = v & 0xffff; c4.w = v >> 16; }
    else { i4.w = (unsigned)-1; const int cl = (clsw >> 24) & 0xff;
           c4.w = (cl >= 2 && s_cnt[cl] > 4096) ? cl + 90 : 0; }
  }
  ((uint4*)out)[q] = i4;
  ((uint4*)(out + NB*OH*OW))[q] = c4;
}

extern "C" void kernel_launch(void* const* d_in, const int* in_sizes, int n_in,
                              void* d_out, int out_size, void* d_ws, size_t ws_size,
                              hipStream_t stream) {
  const float* boxes   = (const float*)d_in[0];
  const int*   classes = (const int*)d_in[1];
  const float* scores  = (const float*)d_in[2];
  const float* dmasks  = (const float*)d_in[3];
  const float* segp    = (const float*)d_in[4];
  int* wsI = (int*)d_ws;
  int* out = (int*)d_out;

  k_segmask<<<128 + NB*ND, 256, 0, stream>>>(boxes, classes, scores, dmasks, segp, wsI, out);
  k_scan   <<<NB*2, 64, 0, stream>>>(wsI);                      // blocks 2,3 zero COUNTS
  k_paint  <<<NB*ND, 256, 0, stream>>>(wsI, out);
  k_resolve<<<(NB*OH*OW)/1024, 256, 0, stream>>>(wsI, out);
}

// Round 10
// 116.630 us; speedup vs baseline: 2.2647x; 1.3606x over previous
//
#include <hip/hip_runtime.h>

#pragma clang fp contract(off)

namespace {
constexpr int NB = 2, ND = 100, MH = 28, MW = 28;
constexpr int OH = 512, OW = 512;
constexpr int SH = 128, SW = 128, NC = 32;
constexpr int BMP_ROWS = 172;
constexpr int BMP8_ROWWORDS = 8;                        // canvas-aligned words per row
constexpr int BMP8_DETWORDS = BMP_ROWS * BMP8_ROWWORDS; // 1376

// workspace layout (int32 word indices)
constexpr int OFF_COUNTS = 0;                     // NB*32
constexpr int OFF_AREA   = 64;                    // NB*ND
constexpr int OFF_ACC    = OFF_AREA + NB*ND;
constexpr int OFF_YB     = OFF_ACC  + NB*ND;
constexpr int OFF_VAL    = OFF_YB   + NB*ND;
constexpr int OFF_QN     = OFF_VAL  + NB*ND;
constexpr int OFF_SEGCLS = OFF_QN   + NB*ND;      // byte region: NB*OH*OW bytes
constexpr int OFF_BMP8   = OFF_SEGCLS + (NB*OH*OW)/4;
constexpr int OCC_STRIDE = 25;                    // odd -> conflict-free; q0+7 <= 22 < 25
constexpr int OCC_WORDS  = OH * OCC_STRIDE;       // 12800 words = 51.2 KB
constexpr int SEGW_TOTAL = (NB*OH*OW)/4;          // 131072 segcls words
constexpr int NHIST      = 128;                   // histogram blocks inside k_scan
constexpr int HIST_WORDS = SEGW_TOTAL / NHIST;    // 1024 words per hist block
static_assert(OFF_BMP8 % 4 == 0, "uint4 alignment");

struct SegSh  { float patch[NC*342]; };                          // 43.8 KB
struct MaskSh { float sc[ND]; float sm[MH*MW]; int det; int area; };
union  K1Sh   { SegSh seg; MaskSh mask; };
}

// ---------------- seg tile: 64x64 out px, LDS-staged 18x18x32 patch (verified r7-r9) ----------------
__device__ __forceinline__ void segTile(int tid, int t, const float* __restrict__ segp,
                                        int* __restrict__ wsI, int* __restrict__ out,
                                        SegSh& S) {
  const int b  = tid >> 6;
  const int tl = tid & 63;
  const int oy = (tl >> 3) * 64, ox = (tl & 7) * 64;
  const int iy0 = (oy >> 2) - 1, ix0 = (ox >> 2) - 1;
  // stage patch: 18x18 px x 8 float4
  for (int idx = t; idx < 18*18*8; idx += 256) {
    const int w  = idx & 7, px = idx >> 3;
    const int pr = px / 18, pc = px - pr*18;
    const int gy = min(max(iy0 + pr, 0), SH-1);
    const int gx = min(max(ix0 + pc, 0), SW-1);
    const float4 v = *(const float4*)(segp + (size_t)((b*SH + gy)*SW + gx)*NC + w*4);
    const int base = pr*19 + pc;
    S.patch[(w*4+0)*342 + base] = v.x;
    S.patch[(w*4+1)*342 + base] = v.y;
    S.patch[(w*4+2)*342 + base] = v.z;
    S.patch[(w*4+3)*342 + base] = v.w;
  }
  __syncthreads();
  const int ty2 = t >> 4, tx2 = t & 15;
  int rlo[4], rhi[4], clo[4], chi[4];
  float fy[4], wy[4], fx[4], wx[4];
  #pragma unroll
  for (int u = 0; u < 4; ++u) {
    const int Y = oy + ty2*4 + u;
    float my = ((float)Y + 0.5f)*0.25f - 0.5f;
    float y0f = floorf(my);
    float f = my - y0f;
    int y0 = (int)y0f, y1 = y0 + 1;
    if (y0 < 0)           { y0 = 0; y1 = 0; f = 0.0f; }
    else if (y1 > SH - 1) { y1 = SH - 1; f = 0.0f; }
    rlo[u] = y0 - iy0; rhi[u] = y1 - iy0; fy[u] = f; wy[u] = 1.0f - f;
  }
  #pragma unroll
  for (int v = 0; v < 4; ++v) {
    const int X = ox + tx2*4 + v;
    float mx = ((float)X + 0.5f)*0.25f - 0.5f;
    float x0f = floorf(mx);
    float f = mx - x0f;
    int x0 = (int)x0f, x1 = x0 + 1;
    if (x0 < 0)           { x0 = 0; x1 = 0; f = 0.0f; }
    else if (x1 > SW - 1) { x1 = SW - 1; f = 0.0f; }
    clo[v] = x0 - ix0; chi[v] = x1 - ix0; fx[v] = f; wx[v] = 1.0f - f;
  }
  const int ro[4] = { rlo[0]*19, rhi[0]*19, rlo[2]*19, rhi[2]*19 };
  const int co[4] = { clo[0],    chi[0],    clo[2],    chi[2]    };
  float best[4][4]; int bcls[4][4];
  #pragma unroll
  for (int u = 0; u < 4; ++u)
    #pragma unroll
    for (int v = 0; v < 4; ++v) { best[u][v] = -3.4e38f; bcls[u][v] = 0; }
  for (int ch = 0; ch < NC; ++ch) {
    const float* P = S.patch + ch*342;
    float tv[4][4];
    #pragma unroll
    for (int i = 0; i < 4; ++i)
      #pragma unroll
      for (int j = 0; j < 4; ++j)
        tv[i][j] = P[ro[i] + co[j]];
    float V[4][4];
    #pragma unroll
    for (int u = 0; u < 4; ++u) {
      const int lo = (u < 2) ? 0 : 2;
      #pragma unroll
      for (int j = 0; j < 4; ++j)
        V[u][j] = wy[u]*tv[lo][j] + fy[u]*tv[lo+1][j];   // vertical first (matches ref)
    }
    #pragma unroll
    for (int u = 0; u < 4; ++u)
      #pragma unroll
      for (int v = 0; v < 4; ++v) {
        const int lo = (v < 2) ? 0 : 2;
        float val = wx[v]*V[u][lo] + fx[v]*V[u][lo+1];
        if (val > best[u][v]) { best[u][v] = val; bcls[u][v] = ch; }  // strict > = first max
      }
  }
  unsigned int* segclsW = (unsigned int*)((char*)wsI + (size_t)OFF_SEGCLS*4);
  const uint4 sent = uint4{0x7FFFFFFFu,0x7FFFFFFFu,0x7FFFFFFFu,0x7FFFFFFFu};
  #pragma unroll
  for (int u = 0; u < 4; ++u) {
    const int Y = oy + ty2*4 + u, X = ox + tx2*4;
    const int pidw = (b*OH*OW + Y*OW + X) >> 2;
    segclsW[pidw] = (unsigned)bcls[u][0] | ((unsigned)bcls[u][1]<<8)
                  | ((unsigned)bcls[u][2]<<16) | ((unsigned)bcls[u][3]<<24);
    *(uint4*)(out + b*OH*OW + Y*OW + X) = sent;          // owner sentinel
  }
}

// ---------------- mask: per-det canvas-aligned bitmap + area (verified r5-r9) ----------------
__device__ __forceinline__ void maskOne(int g, int t, const float* __restrict__ boxes,
                                        const int* __restrict__ classes,
                                        const float* __restrict__ scores,
                                        const float* __restrict__ dmasks,
                                        int* __restrict__ wsI, MaskSh& M) {
  const int b = g / ND, k = g - b*ND;
  if (t < ND) M.sc[t] = scores[b*ND + t];
  if (t == 0) M.area = 0;
  __syncthreads();
  if (t < ND) {
    float sn = M.sc[t];
    int r = 0;
    for (int j = 0; j < ND; ++j) {
      float sj = M.sc[j];
      r += (sj > sn) || (sj == sn && j < t);   // stable descending rank
    }
    if (r == k) M.det = t;
  }
  __syncthreads();
  const int det = M.det;
  const int cls = classes[b*ND + det];
  const float sc = M.sc[det];
  const float* bx = boxes + (size_t)(b*ND + det)*4;
  const float ymin = bx[0], xmin = bx[1], ymax = bx[2], xmax = bx[3];
  const bool keep = (sc > 0.5f) && (cls != 0);
  int ylo = (int)ceilf(ymin), yhi = (int)ceilf(ymax);
  int xlo = (int)ceilf(xmin), xhi = (int)ceilf(xmax);
  ylo = max(ylo, 0); xlo = max(xlo, 0);
  yhi = min(yhi, OH); xhi = min(xhi, OW);
  if (yhi < ylo) yhi = ylo;
  if (xhi < xlo) xhi = xlo;
  if (yhi - ylo > BMP_ROWS) yhi = ylo + BMP_ROWS;
  if (xhi - xlo > 192)      xhi = xlo + 192;
  const int yhi2 = keep ? yhi : ylo, xhi2 = keep ? xhi : xlo;
  const int rows = yhi2 - ylo, width = xhi2 - xlo;
  const int q0 = xlo >> 5;
  const int nw = (width > 0) ? (((xlo & 31) + width + 31) >> 5) : 0;
  if (t == 0) {
    wsI[OFF_YB  + g] = ylo | (yhi2 << 16);
    wsI[OFF_VAL + g] = (det + 1) | (cls << 16);
    wsI[OFF_QN  + g] = q0 | (nw << 16);
  }
  if (rows > 0 && width > 0) {
    const float hs  = (ymax > ymin) ? (28.0f / (ymax - ymin)) : 0.0f;
    const float wsc = (xmax > xmin) ? (28.0f / (xmax - xmin)) : 0.0f;
    const float* mp = dmasks + (size_t)(b*ND + det)*(MH*MW);
    for (int i = t; i < MH*MW; i += 256) M.sm[i] = mp[i];
    __syncthreads();
    unsigned int* bmp8 = (unsigned int*)wsI + OFF_BMP8 + g*BMP8_DETWORDS;
    const int iw = t >> 5, bit = t & 31;
    const int x = ((q0 + iw) << 5) + bit;
    const bool inbox = (x >= xlo) && (x < xhi2);
    for (int r = 0; r < rows; ++r) {
      const int y = ylo + r;
      bool pred = false;
      if (inbox) {
        // exact op order of _paste_one (fp contract off)
        float ty = ((float)y + 0.5f); ty = ty - ymin; ty = ty * hs;  float my = ty - 0.5f;
        float tx = ((float)x + 0.5f); tx = tx - xmin; tx = tx * wsc; float mx = tx - 0.5f;
        float y0f = floorf(my), x0f = floorf(mx);
        float ly = my - y0f, lx = mx - x0f;
        int y0 = (int)y0f, x0 = (int)x0f;
        int y1 = min(max(y0 + 1, 0), MH - 1);
        int x1 = min(max(x0 + 1, 0), MW - 1);
        y0 = min(max(y0, 0), MH - 1);
        x0 = min(max(x0, 0), MW - 1);
        float v00 = M.sm[y0*MW + x0], v01 = M.sm[y0*MW + x1];
        float v10 = M.sm[y1*MW + x0], v11 = M.sm[y1*MW + x1];
        float omlx = 1.0f - lx, omly = 1.0f - ly;
        float top = omlx*v00 + lx*v01;
        float bot = omlx*v10 + lx*v11;
        float outv = omly*top + ly*bot;
        pred = outv > 0.5f;
      }
      unsigned long long m = __ballot(pred);
      unsigned int word = (t & 32) ? (unsigned int)(m >> 32) : (unsigned int)m;
      if (bit == 0) {
        bmp8[r*BMP8_ROWWORDS + iw] = word;
        if (word) atomicAdd(&M.area, __popc(word));
      }
    }
  }
  __syncthreads();
  if (t == 0) wsI[OFF_AREA + g] = (rows > 0 && width > 0) ? M.area : 0;
}

// ================= K1: tiled seg (blocks 0..127) + masks (blocks 128..327) =================
__global__ void __launch_bounds__(256) k_segmask(
    const float* __restrict__ boxes, const int* __restrict__ classes,
    const float* __restrict__ scores, const float* __restrict__ dmasks,
    const float* __restrict__ segp, int* __restrict__ wsI, int* __restrict__ out) {
  __shared__ K1Sh sh;
  const int bid = blockIdx.x, t = threadIdx.x;
  if (bid == 0 && t < 2*NC) wsI[OFF_COUNTS + t] = 0;   // zero class counters (used next kernel)
  if (bid < 128) segTile(bid, t, segp, wsI, out, sh.seg);
  else           maskOne(bid - 128, t, boxes, classes, scores, dmasks, wsI, sh.mask);
}

// ================= K2: scan (blocks 0..1) + stuff histogram (blocks 2..129) =================
namespace {
struct DetReg {
  int gIdx, yb, q0, thr;
  uint4 lo0, hi0, lo1, hi1, lo2, hi2;
};
}

__device__ __forceinline__ void fetchDet(const uint4* __restrict__ bmp4,
                                         const int* s_yb, const int* s_q0, const int* s_thr,
                                         int g, int t, DetReg& D) {
  D.gIdx = g;
  D.yb  = s_yb[g];
  D.q0  = s_q0[g];
  D.thr = s_thr[g];
  const int rows = (D.yb >> 16) - (D.yb & 0xffff);
  const uint4* p = bmp4 + (size_t)g*(BMP8_DETWORDS/4);
  const uint4 z = uint4{0,0,0,0};
  D.lo0 = z; D.hi0 = z; D.lo1 = z; D.hi1 = z; D.lo2 = z; D.hi2 = z;
  if (t < rows)         { D.lo0 = p[t*2];         D.hi0 = p[t*2 + 1]; }
  if (t + 64 < rows)    { D.lo1 = p[(t+64)*2];    D.hi1 = p[(t+64)*2 + 1]; }
  if (t + 128 < rows)   { D.lo2 = p[(t+128)*2];   D.hi2 = p[(t+128)*2 + 1]; }
}

__device__ __forceinline__ int quarterCount(const uint4& lo, const uint4& hi, bool valid,
                                            int rb, const unsigned int* occ,
                                            unsigned int o[8]) {
  int c = 0;
  if (valid) {
    o[0] = occ[rb+0]; o[1] = occ[rb+1]; o[2] = occ[rb+2]; o[3] = occ[rb+3];
    o[4] = occ[rb+4]; o[5] = occ[rb+5]; o[6] = occ[rb+6]; o[7] = occ[rb+7];
    c += __popc(lo.x & o[0]); c += __popc(lo.y & o[1]);
    c += __popc(lo.z & o[2]); c += __popc(lo.w & o[3]);
    c += __popc(hi.x & o[4]); c += __popc(hi.y & o[5]);
    c += __popc(hi.z & o[6]); c += __popc(hi.w & o[7]);
  }
  return c;
}

__device__ __forceinline__ void quarterWrite(const uint4& lo, const uint4& hi, bool valid,
                                             int rb, unsigned int* occ,
                                             const unsigned int o[8]) {
  if (valid) {
    occ[rb+0] = o[0] | lo.x; occ[rb+1] = o[1] | lo.y;
    occ[rb+2] = o[2] | lo.z; occ[rb+3] = o[3] | lo.w;
    occ[rb+4] = o[4] | hi.x; occ[rb+5] = o[5] | hi.y;
    occ[rb+6] = o[6] | hi.z; occ[rb+7] = o[7] | hi.w;
  }
}

__device__ __forceinline__ void processDet(int t, const DetReg& D, unsigned int* occ,
                                           int* __restrict__ accB) {
  const int ylo = D.yb & 0xffff;
  const int rows = (D.yb >> 16) - ylo;
  const bool v0 = t < rows, v1 = t + 64 < rows, v2 = t + 128 < rows;
  const int rb0 = (ylo + t) * OCC_STRIDE + D.q0;
  const int rb1 = rb0 + 64*OCC_STRIDE;
  const int rb2 = rb0 + 128*OCC_STRIDE;
  unsigned int o0[8], o1[8], o2[8];
  int cnt = quarterCount(D.lo0, D.hi0, v0, rb0, occ, o0)
          + quarterCount(D.lo1, D.hi1, v1, rb1, occ, o1)
          + quarterCount(D.lo2, D.hi2, v2, rb2, occ, o2);
  // 64-lane sum via DPP (row_shr 1/2/4/8 + row_bcast15/31), total lands in lane 63
  cnt += __builtin_amdgcn_update_dpp(0, cnt, 0x111, 0xF, 0xF, false);
  cnt += __builtin_amdgcn_update_dpp(0, cnt, 0x112, 0xF, 0xF, false);
  cnt += __builtin_amdgcn_update_dpp(0, cnt, 0x114, 0xF, 0xF, false);
  cnt += __builtin_amdgcn_update_dpp(0, cnt, 0x118, 0xF, 0xF, false);
  cnt += __builtin_amdgcn_update_dpp(0, cnt, 0x142, 0xF, 0xF, false);
  cnt += __builtin_amdgcn_update_dpp(0, cnt, 0x143, 0xF, 0xF, false);
  const int total = __builtin_amdgcn_readlane(cnt, 63);
  if (total < D.thr) {                       // == (float)total/area < 0.5f, by construction
    if (t == 0) accB[D.gIdx] = 1;
    quarterWrite(D.lo0, D.hi0, v0, rb0, occ, o0);
    quarterWrite(D.lo1, D.hi1, v1, rb1, occ, o1);
    quarterWrite(D.lo2, D.hi2, v2, rb2, occ, o2);
  }
}

__global__ void __launch_bounds__(64) k_scan(int* __restrict__ wsI) {
  const int bid = blockIdx.x, t = threadIdx.x;
  if (bid >= NB) {
    // ---- histogram slice (hidden under the serial scan) ----
    __shared__ unsigned int h[2*NC];
    h[t] = 0u;
    __syncthreads();
    const unsigned int* segclsW = (const unsigned int*)((const char*)wsI + (size_t)OFF_SEGCLS*4);
    const int w0 = (bid - NB) * HIST_WORDS;
    const int hb = (w0 >> 16) << 5;            // slice lies in one batch; b*32
    for (int wi = w0 + t; wi < w0 + HIST_WORDS; wi += 64) {
      const unsigned int w = segclsW[wi];
      #pragma unroll
      for (int by = 0; by < 4; ++by) {
        const int cls = (w >> (by*8)) & 0xff;
        if (cls >= 2) atomicAdd(&h[hb + cls], 1u);
      }
    }
    __syncthreads();
    const unsigned int v = h[t];
    if (v) atomicAdd((unsigned int*)&wsI[OFF_COUNTS + t], v);
    return;
  }
  const int b = bid;                          // 1 wave, lockstep, barrier-free main loop
  __shared__ unsigned int occ[OCC_WORDS];     // 51.2 KB
  __shared__ int s_list[ND], s_area[ND], s_yb[ND], s_q0[ND], s_thr[ND];
  for (int i = t; i < OCC_WORDS; i += 64) occ[i] = 0u;
  for (int i = t; i < ND; i += 64) {
    const int area = wsI[OFF_AREA + b*ND + i];
    s_area[i] = area;
    s_yb[i]   = wsI[OFF_YB + b*ND + i];
    s_q0[i]   = wsI[OFF_QN + b*ND + i] & 0xffff;
    int c = 0;
    if (area > 0) {                           // min c with (float)c/area >= 0.5f
      const float a = (float)area;
      c = (area + 1) >> 1;
      while (c > 0 && (float)(c - 1) / a >= 0.5f) --c;
      while ((float)c / a < 0.5f) ++c;
    }
    s_thr[i] = c;
    wsI[OFF_ACC + b*ND + i] = 0;
  }
  __syncthreads();
  int nact = 0;                               // ordered compaction of area>0 dets
  for (int base = 0; base < ND; base += 64) {
    const int i = base + t;
    const bool a = (i < ND) && (s_area[i] > 0);
    unsigned long long m = __ballot(a);
    int pos = nact + __popcll(m & ((1ull << t) - 1ull));
    if (a) s_list[pos] = i;
    nact += (int)__popcll(m);
  }
  __syncthreads();
  if (nact == 0) return;
  const uint4* bmp4 = (const uint4*)((unsigned int*)wsI + OFF_BMP8 + (size_t)b*ND*BMP8_DETWORDS);
  int* accB = wsI + OFF_ACC + b*ND;
  const int last = nact - 1;
  DetReg A, B, C;
  fetchDet(bmp4, s_yb, s_q0, s_thr, s_list[0], t, A);
  fetchDet(bmp4, s_yb, s_q0, s_thr, s_list[min(1, last)], t, B);
  for (int ii = 0; ii < nact; ii += 3) {
    fetchDet(bmp4, s_yb, s_q0, s_thr, s_list[min(ii+2, last)], t, C);
    processDet(t, A, occ, accB);
    fetchDet(bmp4, s_yb, s_q0, s_thr, s_list[min(ii+3, last)], t, A);
    if (ii+1 < nact) processDet(t, B, occ, accB);
    fetchDet(bmp4, s_yb, s_q0, s_thr, s_list[min(ii+4, last)], t, B);
    if (ii+2 < nact) processDet(t, C, occ, accB);
  }
}

// ================= K3: paint owners via atomicMin, 4 rows per iteration =================
__global__ void __launch_bounds__(1024) k_paint(const int* __restrict__ wsI,
                                                int* __restrict__ out) {
  const int g = blockIdx.x;             // b*ND + k
  if (!wsI[OFF_ACC + g]) return;        // uniform
  const int t = threadIdx.x;            // 1024 = 4 rows x 8 words x 32 bits
  const int b = g / ND, k = g - b*ND;
  const int yb = wsI[OFF_YB + g];
  const int ylo = yb & 0xffff;
  const int rows = (yb >> 16) - ylo;
  const int q0 = wsI[OFF_QN + g] & 0xffff;
  const unsigned int* bmp = (const unsigned int*)wsI + OFF_BMP8 + g*BMP8_DETWORDS;
  int* __restrict__ owner = out + b*(OH*OW);     // plane 0 doubles as owner map
  const int rq = t >> 8;                // row quarter 0..3
  const int px = t & 255;
  const int iw = px >> 5, bit = px & 31;
  const int x = ((q0 + iw) << 5) + bit;
  if (x >= OW) return;                  // pad-word lanes carry zero bits
  #pragma unroll 2
  for (int r = rq; r < rows; r += 4) {
    const unsigned int wv = bmp[r*BMP8_ROWWORDS + iw];
    if ((wv >> bit) & 1u)
      atomicMin(&owner[(ylo + r)*OW + x], k);    // owner = min sorted rank == ref
  }
}

// ================= K4: resolve owner -> inst/cat, else stuff (uint4 vectorized) =================
__global__ void k_resolve(const int* __restrict__ wsI, int* __restrict__ out) {
  const int t = threadIdx.x;
  const int q = blockIdx.x*256 + t;      // quad index (4 px)
  const int b = q >> 16;
  __shared__ int s_val[ND];
  __shared__ int s_cnt[NC];
  if (t < ND) s_val[t] = wsI[OFF_VAL + b*ND + t];
  if (t >= 128 && t < 128 + NC) s_cnt[t - 128] = wsI[OFF_COUNTS + b*32 + (t - 128)];
  __syncthreads();
  const uint4 o4 = ((const uint4*)out)[q];
  const unsigned int clsw = ((const unsigned int*)((const char*)wsI + (size_t)OFF_SEGCLS*4))[q];
  uint4 i4, c4;
  {
    const int o = (int)o4.x;
    if (o < ND) { const int v = s_val[o]; i4.x = v & 0xffff; c4.x = v >> 16; }
    else { i4.x = (unsigned)-1; const int cl = clsw & 0xff;
           c4.x = (cl >= 2 && s_cnt[cl] > 4096) ? cl + 90 : 0; }
  }
  {
    const int o = (int)o4.y;
    if (o < ND) { const int v = s_val[o]; i4.y = v & 0xffff; c4.y = v >> 16; }
    else { i4.y = (unsigned)-1; const int cl = (clsw >> 8) & 0xff;
           c4.y = (cl >= 2 && s_cnt[cl] > 4096) ? cl + 90 : 0; }
  }
  {
    const int o = (int)o4.z;
    if (o < ND) { const int v = s_val[o]; i4.z = v & 0xffff; c4.z = v >> 16; }
    else { i4.z = (unsigned)-1; const int cl = (clsw >> 16) & 0xff;
           c4.z = (cl >= 2 && s_cnt[cl] > 4096) ? cl + 90 : 0; }
  }
  {
    const int o = (int)o4.w;
    if (o < ND) { const int v = s_val[o]; i4.w = v & 0xffff; c4.w = v >> 16; }
    else { i4.w = (unsigned)-1; const int cl = (clsw >> 24) & 0xff;
           c4.w = (cl >= 2 && s_cnt[cl] > 4096) ? cl + 90 : 0; }
  }
  ((uint4*)out)[q] = i4;
  ((uint4*)(out + NB*OH*OW))[q] = c4;
}

extern "C" void kernel_launch(void* const* d_in, const int* in_sizes, int n_in,
                              void* d_out, int out_size, void* d_ws, size_t ws_size,
                              hipStream_t stream) {
  const float* boxes   = (const float*)d_in[0];
  const int*   classes = (const int*)d_in[1];
  const float* scores  = (const float*)d_in[2];
  const float* dmasks  = (const float*)d_in[3];
  const float* segp    = (const float*)d_in[4];
  int* wsI = (int*)d_ws;
  int* out = (int*)d_out;

  k_segmask<<<128 + NB*ND, 256, 0, stream>>>(boxes, classes, scores, dmasks, segp, wsI, out);
  k_scan   <<<NB + NHIST, 64, 0, stream>>>(wsI);
  k_paint  <<<NB*ND, 1024, 0, stream>>>(wsI, out);
  k_resolve<<<(NB*OH*OW)/1024, 256, 0, stream>>>(wsI, out);
}

// Round 11
// 89.588 us; speedup vs baseline: 2.9482x; 1.3018x over previous
//
#include <hip/hip_runtime.h>

#pragma clang fp contract(off)

namespace {
constexpr int NB = 2, ND = 100, MH = 28, MW = 28;
constexpr int OH = 512, OW = 512;
constexpr int SH = 128, SW = 128, NC = 32;
constexpr int BMP_ROWS = 172;
constexpr int BMP8_ROWWORDS = 8;                        // canvas-aligned words per row
constexpr int BMP8_DETWORDS = BMP_ROWS * BMP8_ROWWORDS; // 1376

// workspace layout (int32 word indices)
constexpr int OFF_COUNTS = 0;                     // NB*32
constexpr int OFF_AREA   = 64;                    // NB*ND
constexpr int OFF_ACC    = OFF_AREA + NB*ND;
constexpr int OFF_YB     = OFF_ACC  + NB*ND;
constexpr int OFF_VAL    = OFF_YB   + NB*ND;
constexpr int OFF_QN     = OFF_VAL  + NB*ND;
constexpr int OFF_SEGCLS = OFF_QN   + NB*ND;      // byte region: NB*OH*OW bytes
constexpr int OFF_BMP8   = OFF_SEGCLS + (NB*OH*OW)/4;
constexpr int OCC_STRIDE = 25;                    // odd -> conflict-free; q0+7 <= 22 < 25
constexpr int OCC_WORDS  = OH * OCC_STRIDE;       // 12800 words = 51.2 KB
constexpr int SEGW_TOTAL = (NB*OH*OW)/4;          // 131072 segcls words
constexpr int NHIST      = 128;                   // histogram blocks inside k_scan
constexpr int HIST_WORDS = SEGW_TOTAL / NHIST;    // 1024 words per hist block
static_assert(OFF_BMP8 % 4 == 0, "uint4 alignment");

struct SegSh  { float patch[NC*342]; };                          // 43.8 KB
struct MaskSh { float sc[ND]; float sm[MH*MW]; int det; int area; };
union  K1Sh   { SegSh seg; MaskSh mask; };
}

// ---------------- seg tile: 64x64 out px, 1024 thr (1 row x 4 col per thread) ----------------
__device__ __forceinline__ void segTile(int tid, int t, const float* __restrict__ segp,
                                        int* __restrict__ wsI, int* __restrict__ out,
                                        SegSh& S) {
  const int b  = tid >> 6;
  const int tl = tid & 63;
  const int oy = (tl >> 3) * 64, ox = (tl & 7) * 64;
  const int iy0 = (oy >> 2) - 1, ix0 = (ox >> 2) - 1;
  // stage patch: 18x18 px x 8 float4
  for (int idx = t; idx < 18*18*8; idx += 1024) {
    const int w  = idx & 7, px = idx >> 3;
    const int pr = px / 18, pc = px - pr*18;
    const int gy = min(max(iy0 + pr, 0), SH-1);
    const int gx = min(max(ix0 + pc, 0), SW-1);
    const float4 v = *(const float4*)(segp + (size_t)((b*SH + gy)*SW + gx)*NC + w*4);
    const int base = pr*19 + pc;
    S.patch[(w*4+0)*342 + base] = v.x;
    S.patch[(w*4+1)*342 + base] = v.y;
    S.patch[(w*4+2)*342 + base] = v.z;
    S.patch[(w*4+3)*342 + base] = v.w;
  }
  __syncthreads();
  const int ry = t >> 4;                 // 0..63 output row within tile
  const int cq = t & 15;                 // 0..15 col quad
  const int Y = oy + ry;
  // y table (weights exact eighths; clamp -> f=0 single-tap exact)
  float my = ((float)Y + 0.5f)*0.25f - 0.5f;
  float y0f = floorf(my);
  float fy = my - y0f;
  int y0 = (int)y0f, y1 = y0 + 1;
  if (y0 < 0)           { y0 = 0; y1 = 0; fy = 0.0f; }
  else if (y1 > SH - 1) { y1 = SH - 1; fy = 0.0f; }
  const float wy = 1.0f - fy;
  const int ro0 = (y0 - iy0)*19, ro1 = (y1 - iy0)*19;
  // col tables; v01 share x0/x1, v23 share (holds under edge clamps too)
  int co[4]; float fx[4], wx[4];
  {
    int clo[4], chi[4];
    #pragma unroll
    for (int v = 0; v < 4; ++v) {
      const int X = ox + cq*4 + v;
      float mx = ((float)X + 0.5f)*0.25f - 0.5f;
      float x0f = floorf(mx);
      float f = mx - x0f;
      int x0 = (int)x0f, x1 = x0 + 1;
      if (x0 < 0)           { x0 = 0; x1 = 0; f = 0.0f; }
      else if (x1 > SW - 1) { x1 = SW - 1; f = 0.0f; }
      clo[v] = x0 - ix0; chi[v] = x1 - ix0; fx[v] = f; wx[v] = 1.0f - f;
    }
    co[0] = clo[0]; co[1] = chi[0]; co[2] = clo[2]; co[3] = chi[2];
  }
  float best[4]; int bcls[4];
  #pragma unroll
  for (int v = 0; v < 4; ++v) { best[v] = -3.4e38f; bcls[v] = 0; }
  for (int ch = 0; ch < NC; ++ch) {
    const float* P = S.patch + ch*342;
    const float t0 = P[ro0 + co[0]], t1 = P[ro0 + co[1]];
    const float t2 = P[ro0 + co[2]], t3 = P[ro0 + co[3]];
    const float b0 = P[ro1 + co[0]], b1 = P[ro1 + co[1]];
    const float b2 = P[ro1 + co[2]], b3 = P[ro1 + co[3]];
    const float V0 = wy*t0 + fy*b0;      // vertical first (matches ref/XLA dim order)
    const float V1 = wy*t1 + fy*b1;
    const float V2 = wy*t2 + fy*b2;
    const float V3 = wy*t3 + fy*b3;
    const float v0 = wx[0]*V0 + fx[0]*V1;
    const float v1 = wx[1]*V0 + fx[1]*V1;
    const float v2 = wx[2]*V2 + fx[2]*V3;
    const float v3 = wx[3]*V2 + fx[3]*V3;
    if (v0 > best[0]) { best[0] = v0; bcls[0] = ch; }   // strict > = first max
    if (v1 > best[1]) { best[1] = v1; bcls[1] = ch; }
    if (v2 > best[2]) { best[2] = v2; bcls[2] = ch; }
    if (v3 > best[3]) { best[3] = v3; bcls[3] = ch; }
  }
  unsigned int* segclsW = (unsigned int*)((char*)wsI + (size_t)OFF_SEGCLS*4);
  const int X0 = ox + cq*4;
  const int pidw = (b*OH*OW + Y*OW + X0) >> 2;
  segclsW[pidw] = (unsigned)bcls[0] | ((unsigned)bcls[1]<<8)
                | ((unsigned)bcls[2]<<16) | ((unsigned)bcls[3]<<24);
  const uint4 sent = uint4{0x7FFFFFFFu,0x7FFFFFFFu,0x7FFFFFFFu,0x7FFFFFFFu};
  *(uint4*)(out + b*OH*OW + Y*OW + X0) = sent;          // owner sentinel
}

// ---------------- mask: per-det bitmap + area, 4 rows per iteration ----------------
__device__ __forceinline__ void maskOne(int g, int t, const float* __restrict__ boxes,
                                        const int* __restrict__ classes,
                                        const float* __restrict__ scores,
                                        const float* __restrict__ dmasks,
                                        int* __restrict__ wsI, MaskSh& M) {
  const int b = g / ND, k = g - b*ND;
  if (t < ND) M.sc[t] = scores[b*ND + t];
  if (t == 0) M.area = 0;
  __syncthreads();
  if (t < ND) {
    float sn = M.sc[t];
    int r = 0;
    for (int j = 0; j < ND; ++j) {
      float sj = M.sc[j];
      r += (sj > sn) || (sj == sn && j < t);   // stable descending rank
    }
    if (r == k) M.det = t;
  }
  __syncthreads();
  const int det = M.det;
  const int cls = classes[b*ND + det];
  const float sc = M.sc[det];
  const float* bx = boxes + (size_t)(b*ND + det)*4;
  const float ymin = bx[0], xmin = bx[1], ymax = bx[2], xmax = bx[3];
  const bool keep = (sc > 0.5f) && (cls != 0);
  int ylo = (int)ceilf(ymin), yhi = (int)ceilf(ymax);
  int xlo = (int)ceilf(xmin), xhi = (int)ceilf(xmax);
  ylo = max(ylo, 0); xlo = max(xlo, 0);
  yhi = min(yhi, OH); xhi = min(xhi, OW);
  if (yhi < ylo) yhi = ylo;
  if (xhi < xlo) xhi = xlo;
  if (yhi - ylo > BMP_ROWS) yhi = ylo + BMP_ROWS;
  if (xhi - xlo > 192)      xhi = xlo + 192;
  const int yhi2 = keep ? yhi : ylo, xhi2 = keep ? xhi : xlo;
  const int rows = yhi2 - ylo, width = xhi2 - xlo;
  const int q0 = xlo >> 5;
  const int nw = (width > 0) ? (((xlo & 31) + width + 31) >> 5) : 0;
  if (t == 0) {
    wsI[OFF_YB  + g] = ylo | (yhi2 << 16);
    wsI[OFF_VAL + g] = (det + 1) | (cls << 16);
    wsI[OFF_QN  + g] = q0 | (nw << 16);
  }
  if (rows > 0 && width > 0) {
    const float hs  = (ymax > ymin) ? (28.0f / (ymax - ymin)) : 0.0f;
    const float wsc = (xmax > xmin) ? (28.0f / (xmax - xmin)) : 0.0f;
    const float* mp = dmasks + (size_t)(b*ND + det)*(MH*MW);
    for (int i = t; i < MH*MW; i += 1024) M.sm[i] = mp[i];
    __syncthreads();
    unsigned int* bmp8 = (unsigned int*)wsI + OFF_BMP8 + g*BMP8_DETWORDS;
    const int rq = t >> 8;               // row quarter 0..3 (wave-uniform)
    const int px = t & 255;
    const int iw = px >> 5, bit = px & 31;
    const int x = ((q0 + iw) << 5) + bit;
    const bool inbox = (x >= xlo) && (x < xhi2);
    for (int r = rq; r < rows; r += 4) {
      const int y = ylo + r;
      bool pred = false;
      if (inbox) {
        // exact op order of _paste_one (fp contract off)
        float ty = ((float)y + 0.5f); ty = ty - ymin; ty = ty * hs;  float my = ty - 0.5f;
        float tx = ((float)x + 0.5f); tx = tx - xmin; tx = tx * wsc; float mx = tx - 0.5f;
        float y0f = floorf(my), x0f = floorf(mx);
        float ly = my - y0f, lx = mx - x0f;
        int y0 = (int)y0f, x0 = (int)x0f;
        int y1 = min(max(y0 + 1, 0), MH - 1);
        int x1 = min(max(x0 + 1, 0), MW - 1);
        y0 = min(max(y0, 0), MH - 1);
        x0 = min(max(x0, 0), MW - 1);
        float v00 = M.sm[y0*MW + x0], v01 = M.sm[y0*MW + x1];
        float v10 = M.sm[y1*MW + x0], v11 = M.sm[y1*MW + x1];
        float omlx = 1.0f - lx, omly = 1.0f - ly;
        float top = omlx*v00 + lx*v01;
        float bot = omlx*v10 + lx*v11;
        float outv = omly*top + ly*bot;
        pred = outv > 0.5f;
      }
      unsigned long long m = __ballot(pred);
      unsigned int word = (px & 32) ? (unsigned int)(m >> 32) : (unsigned int)m;
      if (bit == 0) {
        bmp8[r*BMP8_ROWWORDS + iw] = word;
        if (word) atomicAdd(&M.area, __popc(word));
      }
    }
  }
  __syncthreads();
  if (t == 0) wsI[OFF_AREA + g] = (rows > 0 && width > 0) ? M.area : 0;
}

// ================= K1: tiled seg (blocks 0..127) + masks (blocks 128..327) =================
__global__ void __launch_bounds__(1024) k_segmask(
    const float* __restrict__ boxes, const int* __restrict__ classes,
    const float* __restrict__ scores, const float* __restrict__ dmasks,
    const float* __restrict__ segp, int* __restrict__ wsI, int* __restrict__ out) {
  __shared__ K1Sh sh;
  const int bid = blockIdx.x, t = threadIdx.x;
  if (bid == 0 && t < 2*NC) wsI[OFF_COUNTS + t] = 0;   // zero class counters (used next kernel)
  if (bid < 128) segTile(bid, t, segp, wsI, out, sh.seg);
  else           maskOne(bid - 128, t, boxes, classes, scores, dmasks, wsI, sh.mask);
}

// ================= K2: scan (blocks 0..1) + stuff histogram (blocks 2..129) =================
namespace {
struct DetReg {
  int gIdx, yb, q0, thr;
  uint4 lo0, hi0, lo1, hi1, lo2, hi2;
};
}

__device__ __forceinline__ void fetchDet(const uint4* __restrict__ bmp4,
                                         const int* s_yb, const int* s_q0, const int* s_thr,
                                         int g, int t, DetReg& D) {
  D.gIdx = g;
  D.yb  = s_yb[g];
  D.q0  = s_q0[g];
  D.thr = s_thr[g];
  const int rows = (D.yb >> 16) - (D.yb & 0xffff);
  const uint4* p = bmp4 + (size_t)g*(BMP8_DETWORDS/4);
  const uint4 z = uint4{0,0,0,0};
  D.lo0 = z; D.hi0 = z; D.lo1 = z; D.hi1 = z; D.lo2 = z; D.hi2 = z;
  if (t < rows)         { D.lo0 = p[t*2];         D.hi0 = p[t*2 + 1]; }
  if (t + 64 < rows)    { D.lo1 = p[(t+64)*2];    D.hi1 = p[(t+64)*2 + 1]; }
  if (t + 128 < rows)   { D.lo2 = p[(t+128)*2];   D.hi2 = p[(t+128)*2 + 1]; }
}

__device__ __forceinline__ int quarterCount(const uint4& lo, const uint4& hi, bool valid,
                                            int rb, const unsigned int* occ,
                                            unsigned int o[8]) {
  int c = 0;
  if (valid) {
    o[0] = occ[rb+0]; o[1] = occ[rb+1]; o[2] = occ[rb+2]; o[3] = occ[rb+3];
    o[4] = occ[rb+4]; o[5] = occ[rb+5]; o[6] = occ[rb+6]; o[7] = occ[rb+7];
    c += __popc(lo.x & o[0]); c += __popc(lo.y & o[1]);
    c += __popc(lo.z & o[2]); c += __popc(lo.w & o[3]);
    c += __popc(hi.x & o[4]); c += __popc(hi.y & o[5]);
    c += __popc(hi.z & o[6]); c += __popc(hi.w & o[7]);
  }
  return c;
}

__device__ __forceinline__ void quarterWrite(const uint4& lo, const uint4& hi, bool valid,
                                             int rb, unsigned int* occ,
                                             const unsigned int o[8]) {
  if (valid) {
    occ[rb+0] = o[0] | lo.x; occ[rb+1] = o[1] | lo.y;
    occ[rb+2] = o[2] | lo.z; occ[rb+3] = o[3] | lo.w;
    occ[rb+4] = o[4] | hi.x; occ[rb+5] = o[5] | hi.y;
    occ[rb+6] = o[6] | hi.z; occ[rb+7] = o[7] | hi.w;
  }
}

__device__ __forceinline__ void processDet(int t, const DetReg& D, unsigned int* occ,
                                           int* __restrict__ accB) {
  const int ylo = D.yb & 0xffff;
  const int rows = (D.yb >> 16) - ylo;
  const bool v0 = t < rows, v1 = t + 64 < rows, v2 = t + 128 < rows;
  const int rb0 = (ylo + t) * OCC_STRIDE + D.q0;
  const int rb1 = rb0 + 64*OCC_STRIDE;
  const int rb2 = rb0 + 128*OCC_STRIDE;
  unsigned int o0[8], o1[8], o2[8];
  int cnt = quarterCount(D.lo0, D.hi0, v0, rb0, occ, o0)
          + quarterCount(D.lo1, D.hi1, v1, rb1, occ, o1)
          + quarterCount(D.lo2, D.hi2, v2, rb2, occ, o2);
  // 64-lane sum via DPP (row_shr 1/2/4/8 + row_bcast15/31), total lands in lane 63
  cnt += __builtin_amdgcn_update_dpp(0, cnt, 0x111, 0xF, 0xF, false);
  cnt += __builtin_amdgcn_update_dpp(0, cnt, 0x112, 0xF, 0xF, false);
  cnt += __builtin_amdgcn_update_dpp(0, cnt, 0x114, 0xF, 0xF, false);
  cnt += __builtin_amdgcn_update_dpp(0, cnt, 0x118, 0xF, 0xF, false);
  cnt += __builtin_amdgcn_update_dpp(0, cnt, 0x142, 0xF, 0xF, false);
  cnt += __builtin_amdgcn_update_dpp(0, cnt, 0x143, 0xF, 0xF, false);
  const int total = __builtin_amdgcn_readlane(cnt, 63);
  if (total < D.thr) {                       // == (float)total/area < 0.5f, by construction
    if (t == 0) accB[D.gIdx] = 1;
    quarterWrite(D.lo0, D.hi0, v0, rb0, occ, o0);
    quarterWrite(D.lo1, D.hi1, v1, rb1, occ, o1);
    quarterWrite(D.lo2, D.hi2, v2, rb2, occ, o2);
  }
}

__global__ void __launch_bounds__(64) k_scan(int* __restrict__ wsI) {
  const int bid = blockIdx.x, t = threadIdx.x;
  if (bid >= NB) {
    // ---- histogram slice (hidden under the serial scan) ----
    __shared__ unsigned int h[2*NC];
    h[t] = 0u;
    __syncthreads();
    const unsigned int* segclsW = (const unsigned int*)((const char*)wsI + (size_t)OFF_SEGCLS*4);
    const int w0 = (bid - NB) * HIST_WORDS;
    const int hb = (w0 >> 16) << 5;            // slice lies in one batch; b*32
    for (int wi = w0 + t; wi < w0 + HIST_WORDS; wi += 64) {
      const unsigned int w = segclsW[wi];
      #pragma unroll
      for (int by = 0; by < 4; ++by) {
        const int cls = (w >> (by*8)) & 0xff;
        if (cls >= 2) atomicAdd(&h[hb + cls], 1u);
      }
    }
    __syncthreads();
    const unsigned int v = h[t];
    if (v) atomicAdd((unsigned int*)&wsI[OFF_COUNTS + t], v);
    return;
  }
  const int b = bid;                          // 1 wave, lockstep, barrier-free main loop
  __shared__ unsigned int occ[OCC_WORDS];     // 51.2 KB
  __shared__ int s_list[ND], s_area[ND], s_yb[ND], s_q0[ND], s_thr[ND];
  for (int i = t; i < OCC_WORDS; i += 64) occ[i] = 0u;
  for (int i = t; i < ND; i += 64) {
    const int area = wsI[OFF_AREA + b*ND + i];
    s_area[i] = area;
    s_yb[i]   = wsI[OFF_YB + b*ND + i];
    s_q0[i]   = wsI[OFF_QN + b*ND + i] & 0xffff;
    int c = 0;
    if (area > 0) {                           // min c with (float)c/area >= 0.5f
      const float a = (float)area;
      c = (area + 1) >> 1;
      while (c > 0 && (float)(c - 1) / a >= 0.5f) --c;
      while ((float)c / a < 0.5f) ++c;
    }
    s_thr[i] = c;
    wsI[OFF_ACC + b*ND + i] = 0;
  }
  __syncthreads();
  int nact = 0;                               // ordered compaction of area>0 dets
  for (int base = 0; base < ND; base += 64) {
    const int i = base + t;
    const bool a = (i < ND) && (s_area[i] > 0);
    unsigned long long m = __ballot(a);
    int pos = nact + __popcll(m & ((1ull << t) - 1ull));
    if (a) s_list[pos] = i;
    nact += (int)__popcll(m);
  }
  __syncthreads();
  if (nact == 0) return;
  const uint4* bmp4 = (const uint4*)((unsigned int*)wsI + OFF_BMP8 + (size_t)b*ND*BMP8_DETWORDS);
  int* accB = wsI + OFF_ACC + b*ND;
  const int last = nact - 1;
  DetReg A, B, C;
  fetchDet(bmp4, s_yb, s_q0, s_thr, s_list[0], t, A);
  fetchDet(bmp4, s_yb, s_q0, s_thr, s_list[min(1, last)], t, B);
  for (int ii = 0; ii < nact; ii += 3) {
    fetchDet(bmp4, s_yb, s_q0, s_thr, s_list[min(ii+2, last)], t, C);
    processDet(t, A, occ, accB);
    fetchDet(bmp4, s_yb, s_q0, s_thr, s_list[min(ii+3, last)], t, A);
    if (ii+1 < nact) processDet(t, B, occ, accB);
    fetchDet(bmp4, s_yb, s_q0, s_thr, s_list[min(ii+4, last)], t, B);
    if (ii+2 < nact) processDet(t, C, occ, accB);
  }
}

// ================= K3: paint owners via atomicMin, 4 rows per iteration =================
__global__ void __launch_bounds__(1024) k_paint(const int* __restrict__ wsI,
                                                int* __restrict__ out) {
  const int g = blockIdx.x;             // b*ND + k
  if (!wsI[OFF_ACC + g]) return;        // uniform
  const int t = threadIdx.x;            // 1024 = 4 rows x 8 words x 32 bits
  const int b = g / ND, k = g - b*ND;
  const int yb = wsI[OFF_YB + g];
  const int ylo = yb & 0xffff;
  const int rows = (yb >> 16) - ylo;
  const int q0 = wsI[OFF_QN + g] & 0xffff;
  const unsigned int* bmp = (const unsigned int*)wsI + OFF_BMP8 + g*BMP8_DETWORDS;
  int* __restrict__ owner = out + b*(OH*OW);     // plane 0 doubles as owner map
  const int rq = t >> 8;                // row quarter 0..3
  const int px = t & 255;
  const int iw = px >> 5, bit = px & 31;
  const int x = ((q0 + iw) << 5) + bit;
  if (x >= OW) return;                  // pad-word lanes carry zero bits
  #pragma unroll 2
  for (int r = rq; r < rows; r += 4) {
    const unsigned int wv = bmp[r*BMP8_ROWWORDS + iw];
    if ((wv >> bit) & 1u)
      atomicMin(&owner[(ylo + r)*OW + x], k);    // owner = min sorted rank == ref
  }
}

// ================= K4: resolve owner -> inst/cat, else stuff (uint4 vectorized) =================
__global__ void k_resolve(const int* __restrict__ wsI, int* __restrict__ out) {
  const int t = threadIdx.x;
  const int q = blockIdx.x*256 + t;      // quad index (4 px)
  const int b = q >> 16;
  __shared__ int s_val[ND];
  __shared__ int s_cnt[NC];
  if (t < ND) s_val[t] = wsI[OFF_VAL + b*ND + t];
  if (t >= 128 && t < 128 + NC) s_cnt[t - 128] = wsI[OFF_COUNTS + b*32 + (t - 128)];
  __syncthreads();
  const uint4 o4 = ((const uint4*)out)[q];
  const unsigned int clsw = ((const unsigned int*)((const char*)wsI + (size_t)OFF_SEGCLS*4))[q];
  uint4 i4, c4;
  {
    const int o = (int)o4.x;
    if (o < ND) { const int v = s_val[o]; i4.x = v & 0xffff; c4.x = v >> 16; }
    else { i4.x = (unsigned)-1; const int cl = clsw & 0xff;
           c4.x = (cl >= 2 && s_cnt[cl] > 4096) ? cl + 90 : 0; }
  }
  {
    const int o = (int)o4.y;
    if (o < ND) { const int v = s_val[o]; i4.y = v & 0xffff; c4.y = v >> 16; }
    else { i4.y = (unsigned)-1; const int cl = (clsw >> 8) & 0xff;
           c4.y = (cl >= 2 && s_cnt[cl] > 4096) ? cl + 90 : 0; }
  }
  {
    const int o = (int)o4.z;
    if (o < ND) { const int v = s_val[o]; i4.z = v & 0xffff; c4.z = v >> 16; }
    else { i4.z = (unsigned)-1; const int cl = (clsw >> 16) & 0xff;
           c4.z = (cl >= 2 && s_cnt[cl] > 4096) ? cl + 90 : 0; }
  }
  {
    const int o = (int)o4.w;
    if (o < ND) { const int v = s_val[o]; i4.w = v & 0xffff; c4.w = v >> 16; }
    else { i4.w = (unsigned)-1; const int cl = (clsw >> 24) & 0xff;
           c4.w = (cl >= 2 && s_cnt[cl] > 4096) ? cl + 90 : 0; }
  }
  ((uint4*)out)[q] = i4;
  ((uint4*)(out + NB*OH*OW))[q] = c4;
}

extern "C" void kernel_launch(void* const* d_in, const int* in_sizes, int n_in,
                              void* d_out, int out_size, void* d_ws, size_t ws_size,
                              hipStream_t stream) {
  const float* boxes   = (const float*)d_in[0];
  const int*   classes = (const int*)d_in[1];
  const float* scores  = (const float*)d_in[2];
  const float* dmasks  = (const float*)d_in[3];
  const float* segp    = (const float*)d_in[4];
  int* wsI = (int*)d_ws;
  int* out = (int*)d_out;

  k_segmask<<<128 + NB*ND, 1024, 0, stream>>>(boxes, classes, scores, dmasks, segp, wsI, out);
  k_scan   <<<NB + NHIST, 64, 0, stream>>>(wsI);
  k_paint  <<<NB*ND, 1024, 0, stream>>>(wsI, out);
  k_resolve<<<(NB*OH*OW)/1024, 256, 0, stream>>>(wsI, out);
}

// Round 12
// 89.260 us; speedup vs baseline: 2.9591x; 1.0037x over previous
//
#include <hip/hip_runtime.h>

#pragma clang fp contract(off)

namespace {
constexpr int NB = 2, ND = 100, MH = 28, MW = 28;
constexpr int OH = 512, OW = 512;
constexpr int SH = 128, SW = 128, NC = 32;
constexpr int BMP_ROWS = 172;
constexpr int BMP8_ROWWORDS = 8;                        // canvas-aligned words per row
constexpr int BMP8_DETWORDS = BMP_ROWS * BMP8_ROWWORDS; // 1376

// workspace layout (int32 word indices)
constexpr int OFF_COUNTS = 0;                     // NB*32
constexpr int OFF_AREA   = 64;                    // NB*ND
constexpr int OFF_ACC    = OFF_AREA + NB*ND;
constexpr int OFF_YB     = OFF_ACC  + NB*ND;
constexpr int OFF_VAL    = OFF_YB   + NB*ND;
constexpr int OFF_QN     = OFF_VAL  + NB*ND;
constexpr int OFF_SEGCLS = OFF_QN   + NB*ND;      // byte region: NB*OH*OW bytes
constexpr int OFF_BMP8   = OFF_SEGCLS + (NB*OH*OW)/4;
constexpr int OCC_STRIDE = 25;                    // odd -> conflict-free; q0+7 <= 22 < 25
constexpr int OCC_WORDS  = OH * OCC_STRIDE;       // 12800 words = 51.2 KB
constexpr int SEGW_TOTAL = (NB*OH*OW)/4;          // 131072 segcls words
constexpr int NHIST      = 128;                   // histogram blocks inside k_scan
constexpr int HIST_WORDS = SEGW_TOTAL / NHIST;    // 1024 words per hist block
static_assert(OFF_BMP8 % 4 == 0, "uint4 alignment");

struct SegSh  { float patch[NC*342]; };                          // 43.8 KB
struct MaskSh { float sc[ND]; float sm[MH*MW]; int det; int area; };
union  K1Sh   { SegSh seg; MaskSh mask; };
}

// ---------------- seg tile: 64x64 out px, 1024 thr (1 row x 4 col per thread) ----------------
__device__ __forceinline__ void segTile(int tid, int t, const float* __restrict__ segp,
                                        int* __restrict__ wsI, int* __restrict__ out,
                                        SegSh& S) {
  const int b  = tid >> 6;
  const int tl = tid & 63;
  const int oy = (tl >> 3) * 64, ox = (tl & 7) * 64;
  const int iy0 = (oy >> 2) - 1, ix0 = (ox >> 2) - 1;
  // stage patch: 18x18 px x 8 float4
  for (int idx = t; idx < 18*18*8; idx += 1024) {
    const int w  = idx & 7, px = idx >> 3;
    const int pr = px / 18, pc = px - pr*18;
    const int gy = min(max(iy0 + pr, 0), SH-1);
    const int gx = min(max(ix0 + pc, 0), SW-1);
    const float4 v = *(const float4*)(segp + (size_t)((b*SH + gy)*SW + gx)*NC + w*4);
    const int base = pr*19 + pc;
    S.patch[(w*4+0)*342 + base] = v.x;
    S.patch[(w*4+1)*342 + base] = v.y;
    S.patch[(w*4+2)*342 + base] = v.z;
    S.patch[(w*4+3)*342 + base] = v.w;
  }
  __syncthreads();
  const int ry = t >> 4;                 // 0..63 output row within tile
  const int cq = t & 15;                 // 0..15 col quad
  const int Y = oy + ry;
  // y table (weights exact eighths; clamp -> f=0 single-tap exact)
  float my = ((float)Y + 0.5f)*0.25f - 0.5f;
  float y0f = floorf(my);
  float fy = my - y0f;
  int y0 = (int)y0f, y1 = y0 + 1;
  if (y0 < 0)           { y0 = 0; y1 = 0; fy = 0.0f; }
  else if (y1 > SH - 1) { y1 = SH - 1; fy = 0.0f; }
  const float wy = 1.0f - fy;
  const int ro0 = (y0 - iy0)*19, ro1 = (y1 - iy0)*19;
  // col tables; v01 share x0/x1, v23 share (holds under edge clamps too)
  int co[4]; float fx[4], wx[4];
  {
    int clo[4], chi[4];
    #pragma unroll
    for (int v = 0; v < 4; ++v) {
      const int X = ox + cq*4 + v;
      float mx = ((float)X + 0.5f)*0.25f - 0.5f;
      float x0f = floorf(mx);
      float f = mx - x0f;
      int x0 = (int)x0f, x1 = x0 + 1;
      if (x0 < 0)           { x0 = 0; x1 = 0; f = 0.0f; }
      else if (x1 > SW - 1) { x1 = SW - 1; f = 0.0f; }
      clo[v] = x0 - ix0; chi[v] = x1 - ix0; fx[v] = f; wx[v] = 1.0f - f;
    }
    co[0] = clo[0]; co[1] = chi[0]; co[2] = clo[2]; co[3] = chi[2];
  }
  float best[4]; int bcls[4];
  #pragma unroll
  for (int v = 0; v < 4; ++v) { best[v] = -3.4e38f; bcls[v] = 0; }
  for (int ch = 0; ch < NC; ++ch) {
    const float* P = S.patch + ch*342;
    const float t0 = P[ro0 + co[0]], t1 = P[ro0 + co[1]];
    const float t2 = P[ro0 + co[2]], t3 = P[ro0 + co[3]];
    const float b0 = P[ro1 + co[0]], b1 = P[ro1 + co[1]];
    const float b2 = P[ro1 + co[2]], b3 = P[ro1 + co[3]];
    const float V0 = wy*t0 + fy*b0;      // vertical first (matches ref/XLA dim order)
    const float V1 = wy*t1 + fy*b1;
    const float V2 = wy*t2 + fy*b2;
    const float V3 = wy*t3 + fy*b3;
    const float v0 = wx[0]*V0 + fx[0]*V1;
    const float v1 = wx[1]*V0 + fx[1]*V1;
    const float v2 = wx[2]*V2 + fx[2]*V3;
    const float v3 = wx[3]*V2 + fx[3]*V3;
    if (v0 > best[0]) { best[0] = v0; bcls[0] = ch; }   // strict > = first max
    if (v1 > best[1]) { best[1] = v1; bcls[1] = ch; }
    if (v2 > best[2]) { best[2] = v2; bcls[2] = ch; }
    if (v3 > best[3]) { best[3] = v3; bcls[3] = ch; }
  }
  unsigned int* segclsW = (unsigned int*)((char*)wsI + (size_t)OFF_SEGCLS*4);
  const int X0 = ox + cq*4;
  const int pidw = (b*OH*OW + Y*OW + X0) >> 2;
  segclsW[pidw] = (unsigned)bcls[0] | ((unsigned)bcls[1]<<8)
                | ((unsigned)bcls[2]<<16) | ((unsigned)bcls[3]<<24);
  const uint4 sent = uint4{0x7FFFFFFFu,0x7FFFFFFFu,0x7FFFFFFFu,0x7FFFFFFFu};
  *(uint4*)(out + b*OH*OW + Y*OW + X0) = sent;          // owner sentinel
}

// ---------------- mask: per-det bitmap + area, 4 rows per iteration ----------------
__device__ __forceinline__ void maskOne(int g, int t, const float* __restrict__ boxes,
                                        const int* __restrict__ classes,
                                        const float* __restrict__ scores,
                                        const float* __restrict__ dmasks,
                                        int* __restrict__ wsI, MaskSh& M) {
  const int b = g / ND, k = g - b*ND;
  if (t < ND) M.sc[t] = scores[b*ND + t];
  if (t == 0) M.area = 0;
  __syncthreads();
  if (t < ND) {
    float sn = M.sc[t];
    int r = 0;
    for (int j = 0; j < ND; ++j) {
      float sj = M.sc[j];
      r += (sj > sn) || (sj == sn && j < t);   // stable descending rank
    }
    if (r == k) M.det = t;
  }
  __syncthreads();
  const int det = M.det;
  const int cls = classes[b*ND + det];
  const float sc = M.sc[det];
  const float* bx = boxes + (size_t)(b*ND + det)*4;
  const float ymin = bx[0], xmin = bx[1], ymax = bx[2], xmax = bx[3];
  const bool keep = (sc > 0.5f) && (cls != 0);
  int ylo = (int)ceilf(ymin), yhi = (int)ceilf(ymax);
  int xlo = (int)ceilf(xmin), xhi = (int)ceilf(xmax);
  ylo = max(ylo, 0); xlo = max(xlo, 0);
  yhi = min(yhi, OH); xhi = min(xhi, OW);
  if (yhi < ylo) yhi = ylo;
  if (xhi < xlo) xhi = xlo;
  if (yhi - ylo > BMP_ROWS) yhi = ylo + BMP_ROWS;
  if (xhi - xlo > 192)      xhi = xlo + 192;
  const int yhi2 = keep ? yhi : ylo, xhi2 = keep ? xhi : xlo;
  const int rows = yhi2 - ylo, width = xhi2 - xlo;
  const int q0 = xlo >> 5;
  const int nw = (width > 0) ? (((xlo & 31) + width + 31) >> 5) : 0;
  if (t == 0) {
    wsI[OFF_YB  + g] = ylo | (yhi2 << 16);
    wsI[OFF_VAL + g] = (det + 1) | (cls << 16);
    wsI[OFF_QN  + g] = q0 | (nw << 16);
  }
  if (rows > 0 && width > 0) {
    const float hs  = (ymax > ymin) ? (28.0f / (ymax - ymin)) : 0.0f;
    const float wsc = (xmax > xmin) ? (28.0f / (xmax - xmin)) : 0.0f;
    const float* mp = dmasks + (size_t)(b*ND + det)*(MH*MW);
    for (int i = t; i < MH*MW; i += 1024) M.sm[i] = mp[i];
    __syncthreads();
    unsigned int* bmp8 = (unsigned int*)wsI + OFF_BMP8 + g*BMP8_DETWORDS;
    const int rq = t >> 8;               // row quarter 0..3 (wave-uniform)
    const int px = t & 255;
    const int iw = px >> 5, bit = px & 31;
    const int x = ((q0 + iw) << 5) + bit;
    const bool inbox = (x >= xlo) && (x < xhi2);
    for (int r = rq; r < rows; r += 4) {
      const int y = ylo + r;
      bool pred = false;
      if (inbox) {
        // exact op order of _paste_one (fp contract off)
        float ty = ((float)y + 0.5f); ty = ty - ymin; ty = ty * hs;  float my = ty - 0.5f;
        float tx = ((float)x + 0.5f); tx = tx - xmin; tx = tx * wsc; float mx = tx - 0.5f;
        float y0f = floorf(my), x0f = floorf(mx);
        float ly = my - y0f, lx = mx - x0f;
        int y0 = (int)y0f, x0 = (int)x0f;
        int y1 = min(max(y0 + 1, 0), MH - 1);
        int x1 = min(max(x0 + 1, 0), MW - 1);
        y0 = min(max(y0, 0), MH - 1);
        x0 = min(max(x0, 0), MW - 1);
        float v00 = M.sm[y0*MW + x0], v01 = M.sm[y0*MW + x1];
        float v10 = M.sm[y1*MW + x0], v11 = M.sm[y1*MW + x1];
        float omlx = 1.0f - lx, omly = 1.0f - ly;
        float top = omlx*v00 + lx*v01;
        float bot = omlx*v10 + lx*v11;
        float outv = omly*top + ly*bot;
        pred = outv > 0.5f;
      }
      unsigned long long m = __ballot(pred);
      unsigned int word = (px & 32) ? (unsigned int)(m >> 32) : (unsigned int)m;
      if (bit == 0) {
        bmp8[r*BMP8_ROWWORDS + iw] = word;
        if (word) atomicAdd(&M.area, __popc(word));
      }
    }
  }
  __syncthreads();
  if (t == 0) wsI[OFF_AREA + g] = (rows > 0 && width > 0) ? M.area : 0;
}

// ================= K1: tiled seg (blocks 0..127) + masks (blocks 128..327) =================
__global__ void __launch_bounds__(1024) k_segmask(
    const float* __restrict__ boxes, const int* __restrict__ classes,
    const float* __restrict__ scores, const float* __restrict__ dmasks,
    const float* __restrict__ segp, int* __restrict__ wsI, int* __restrict__ out) {
  __shared__ K1Sh sh;
  const int bid = blockIdx.x, t = threadIdx.x;
  if (bid == 0 && t < 2*NC) wsI[OFF_COUNTS + t] = 0;   // zero class counters (used next kernel)
  if (bid < 128) segTile(bid, t, segp, wsI, out, sh.seg);
  else           maskOne(bid - 128, t, boxes, classes, scores, dmasks, wsI, sh.mask);
}

// ================= K2: scan (blocks 0..1) + stuff histogram (blocks 2..129) =================
namespace {
struct DetReg {
  int g, yb, q0, thr;
  uint4 lo0, hi0, lo1, hi1, lo2, hi2;
};
}

__device__ __forceinline__ void fetchD(int yb, int aux, int t,
                                       const uint4* __restrict__ bmp4, DetReg& D) {
  D.yb  = yb;
  D.q0  = aux & 15;
  D.g   = (aux >> 4) & 127;
  D.thr = aux >> 11;
  const int rows = (yb >> 16) - (yb & 0xffff);
  const uint4* p = bmp4 + (size_t)D.g*(BMP8_DETWORDS/4);
  const uint4 z = uint4{0,0,0,0};
  D.lo0 = z; D.hi0 = z; D.lo1 = z; D.hi1 = z; D.lo2 = z; D.hi2 = z;
  if (t < rows)         { D.lo0 = p[t*2];         D.hi0 = p[t*2 + 1]; }
  if (t + 64 < rows)    { D.lo1 = p[(t+64)*2];    D.hi1 = p[(t+64)*2 + 1]; }
  if (t + 128 < rows)   { D.lo2 = p[(t+128)*2];   D.hi2 = p[(t+128)*2 + 1]; }
}

__device__ __forceinline__ int quarterCount(const uint4& lo, const uint4& hi, bool valid,
                                            int rb, const unsigned int* occ,
                                            unsigned int o[8]) {
  int c = 0;
  if (valid) {
    o[0] = occ[rb+0]; o[1] = occ[rb+1]; o[2] = occ[rb+2]; o[3] = occ[rb+3];
    o[4] = occ[rb+4]; o[5] = occ[rb+5]; o[6] = occ[rb+6]; o[7] = occ[rb+7];
    c += __popc(lo.x & o[0]); c += __popc(lo.y & o[1]);
    c += __popc(lo.z & o[2]); c += __popc(lo.w & o[3]);
    c += __popc(hi.x & o[4]); c += __popc(hi.y & o[5]);
    c += __popc(hi.z & o[6]); c += __popc(hi.w & o[7]);
  }
  return c;
}

__device__ __forceinline__ void quarterWrite(const uint4& lo, const uint4& hi, bool valid,
                                             int rb, unsigned int* occ,
                                             const unsigned int o[8]) {
  if (valid) {
    occ[rb+0] = o[0] | lo.x; occ[rb+1] = o[1] | lo.y;
    occ[rb+2] = o[2] | lo.z; occ[rb+3] = o[3] | lo.w;
    occ[rb+4] = o[4] | hi.x; occ[rb+5] = o[5] | hi.y;
    occ[rb+6] = o[6] | hi.z; occ[rb+7] = o[7] | hi.w;
  }
}

__device__ __forceinline__ void processDet(int t, const DetReg& D, unsigned int* occ,
                                           int* __restrict__ accB) {
  const int ylo = D.yb & 0xffff;
  const int rows = (D.yb >> 16) - ylo;
  const bool v0 = t < rows, v1 = t + 64 < rows, v2 = t + 128 < rows;
  const int rb0 = (ylo + t) * OCC_STRIDE + D.q0;
  const int rb1 = rb0 + 64*OCC_STRIDE;
  const int rb2 = rb0 + 128*OCC_STRIDE;
  unsigned int o0[8], o1[8], o2[8];
  int cnt = quarterCount(D.lo0, D.hi0, v0, rb0, occ, o0)
          + quarterCount(D.lo1, D.hi1, v1, rb1, occ, o1)
          + quarterCount(D.lo2, D.hi2, v2, rb2, occ, o2);
  // 64-lane sum via DPP (row_shr 1/2/4/8 + row_bcast15/31), total lands in lane 63
  cnt += __builtin_amdgcn_update_dpp(0, cnt, 0x111, 0xF, 0xF, false);
  cnt += __builtin_amdgcn_update_dpp(0, cnt, 0x112, 0xF, 0xF, false);
  cnt += __builtin_amdgcn_update_dpp(0, cnt, 0x114, 0xF, 0xF, false);
  cnt += __builtin_amdgcn_update_dpp(0, cnt, 0x118, 0xF, 0xF, false);
  cnt += __builtin_amdgcn_update_dpp(0, cnt, 0x142, 0xF, 0xF, false);
  cnt += __builtin_amdgcn_update_dpp(0, cnt, 0x143, 0xF, 0xF, false);
  const int total = __builtin_amdgcn_readlane(cnt, 63);
  if (total < D.thr) {                       // == (float)total/area < 0.5f, by construction
    if (t == 0) accB[D.g] = 1;
    quarterWrite(D.lo0, D.hi0, v0, rb0, occ, o0);
    quarterWrite(D.lo1, D.hi1, v1, rb1, occ, o1);
    quarterWrite(D.lo2, D.hi2, v2, rb2, occ, o2);
  }
}

__global__ void __launch_bounds__(64) k_scan(int* __restrict__ wsI) {
  const int bid = blockIdx.x, t = threadIdx.x;
  if (bid >= NB) {
    // ---- histogram slice (hidden under the serial scan) ----
    __shared__ unsigned int h[2*NC];
    h[t] = 0u;
    __syncthreads();
    const unsigned int* segclsW = (const unsigned int*)((const char*)wsI + (size_t)OFF_SEGCLS*4);
    const int w0 = (bid - NB) * HIST_WORDS;
    const int hb = (w0 >> 16) << 5;            // slice lies in one batch; b*32
    for (int wi = w0 + t; wi < w0 + HIST_WORDS; wi += 64) {
      const unsigned int w = segclsW[wi];
      #pragma unroll
      for (int by = 0; by < 4; ++by) {
        const int cls = (w >> (by*8)) & 0xff;
        if (cls >= 2) atomicAdd(&h[hb + cls], 1u);
      }
    }
    __syncthreads();
    const unsigned int v = h[t];
    if (v) atomicAdd((unsigned int*)&wsI[OFF_COUNTS + t], v);
    return;
  }
  const int b = bid;                          // 1 wave, lockstep, barrier-free main loop
  __shared__ unsigned int occ[OCC_WORDS];     // 51.2 KB
  __shared__ int s_list[ND];
  for (int i = t; i < OCC_WORDS; i += 64) occ[i] = 0u;
  // areas / acc-zero (dets t and t+64)
  const int a0 = (t < ND)      ? wsI[OFF_AREA + b*ND + t]      : 0;
  const int a1 = (t + 64 < ND) ? wsI[OFF_AREA + b*ND + t + 64] : 0;
  if (t < ND)      wsI[OFF_ACC + b*ND + t] = 0;
  if (t + 64 < ND) wsI[OFF_ACC + b*ND + t + 64] = 0;
  // ordered compaction of area>0 dets into s_list (sorted-rank order preserved)
  int nact;
  {
    const bool k0 = (t < ND) && (a0 > 0);
    const unsigned long long m0 = __ballot(k0);
    if (k0) s_list[__popcll(m0 & ((1ull << t) - 1ull))] = t;
    nact = (int)__popcll(m0);
    const bool k1 = (t + 64 < ND) && (a1 > 0);
    const unsigned long long m1 = __ballot(k1);
    if (k1) s_list[nact + __popcll(m1 & ((1ull << t) - 1ull))] = t + 64;
    nact += (int)__popcll(m1);
  }
  __syncthreads();
  if (nact == 0) return;
  // pre-permuted per-lane metadata: lane l holds active det l (and l+64)
  int myb0 = 0, maux0 = 0, myb1 = 0, maux1 = 0;
  if (t < nact) {
    const int g = s_list[t];
    myb0 = wsI[OFF_YB + b*ND + g];
    const int q0 = wsI[OFF_QN + b*ND + g] & 0xffff;
    const int area = wsI[OFF_AREA + b*ND + g];
    int c = (area + 1) >> 1;                  // min c with (float)c/area >= 0.5f
    const float a = (float)area;
    while (c > 0 && (float)(c - 1) / a >= 0.5f) --c;
    while ((float)c / a < 0.5f) ++c;
    maux0 = q0 | (g << 4) | (c << 11);
  }
  if (t + 64 < nact) {
    const int g = s_list[t + 64];
    myb1 = wsI[OFF_YB + b*ND + g];
    const int q0 = wsI[OFF_QN + b*ND + g] & 0xffff;
    const int area = wsI[OFF_AREA + b*ND + g];
    int c = (area + 1) >> 1;
    const float a = (float)area;
    while (c > 0 && (float)(c - 1) / a >= 0.5f) --c;
    while ((float)c / a < 0.5f) ++c;
    maux1 = q0 | (g << 4) | (c << 11);
  }
  const uint4* bmp4 = (const uint4*)((unsigned int*)wsI + OFF_BMP8 + (size_t)b*ND*BMP8_DETWORDS);
  int* accB = wsI + OFF_ACC + b*ND;
  const int last = nact - 1;
  // uniform metadata access: few-cycle readlane instead of LDS round-trips
  #define MYB(ii)  ((ii) < 64 ? __builtin_amdgcn_readlane(myb0,  (ii)) \
                              : __builtin_amdgcn_readlane(myb1,  (ii) - 64))
  #define MAUX(ii) ((ii) < 64 ? __builtin_amdgcn_readlane(maux0, (ii)) \
                              : __builtin_amdgcn_readlane(maux1, (ii) - 64))
  DetReg A, B, C, D;
  { int i0 = 0;              fetchD(MYB(i0), MAUX(i0), t, bmp4, A); }
  { int i1 = min(1, last);   fetchD(MYB(i1), MAUX(i1), t, bmp4, B); }
  { int i2 = min(2, last);   fetchD(MYB(i2), MAUX(i2), t, bmp4, C); }
  { int i3 = min(3, last);   fetchD(MYB(i3), MAUX(i3), t, bmp4, D); }
  for (int ii = 0; ii < nact; ii += 4) {
    processDet(t, A, occ, accB);
    { const int n = min(ii + 4, last); fetchD(MYB(n), MAUX(n), t, bmp4, A); }
    if (ii + 1 < nact) processDet(t, B, occ, accB);
    { const int n = min(ii + 5, last); fetchD(MYB(n), MAUX(n), t, bmp4, B); }
    if (ii + 2 < nact) processDet(t, C, occ, accB);
    { const int n = min(ii + 6, last); fetchD(MYB(n), MAUX(n), t, bmp4, C); }
    if (ii + 3 < nact) processDet(t, D, occ, accB);
    { const int n = min(ii + 7, last); fetchD(MYB(n), MAUX(n), t, bmp4, D); }
  }
  #undef MYB
  #undef MAUX
}

// ================= K3: paint owners via atomicMin, 4 rows per iteration =================
__global__ void __launch_bounds__(1024) k_paint(const int* __restrict__ wsI,
                                                int* __restrict__ out) {
  const int g = blockIdx.x;             // b*ND + k
  if (!wsI[OFF_ACC + g]) return;        // uniform
  const int t = threadIdx.x;            // 1024 = 4 rows x 8 words x 32 bits
  const int b = g / ND, k = g - b*ND;
  const int yb = wsI[OFF_YB + g];
  const int ylo = yb & 0xffff;
  const int rows = (yb >> 16) - ylo;
  const int q0 = wsI[OFF_QN + g] & 0xffff;
  const unsigned int* bmp = (const unsigned int*)wsI + OFF_BMP8 + g*BMP8_DETWORDS;
  int* __restrict__ owner = out + b*(OH*OW);     // plane 0 doubles as owner map
  const int rq = t >> 8;                // row quarter 0..3
  const int px = t & 255;
  const int iw = px >> 5, bit = px & 31;
  const int x = ((q0 + iw) << 5) + bit;
  if (x >= OW) return;                  // pad-word lanes carry zero bits
  #pragma unroll 2
  for (int r = rq; r < rows; r += 4) {
    const unsigned int wv = bmp[r*BMP8_ROWWORDS + iw];
    if ((wv >> bit) & 1u)
      atomicMin(&owner[(ylo + r)*OW + x], k);    // owner = min sorted rank == ref
  }
}

// ================= K4: resolve owner -> inst/cat, else stuff (uint4 vectorized) =================
__global__ void k_resolve(const int* __restrict__ wsI, int* __restrict__ out) {
  const int t = threadIdx.x;
  const int q = blockIdx.x*256 + t;      // quad index (4 px)
  const int b = q >> 16;
  __shared__ int s_val[ND];
  __shared__ int s_cnt[NC];
  if (t < ND) s_val[t] = wsI[OFF_VAL + b*ND + t];
  if (t >= 128 && t < 128 + NC) s_cnt[t - 128] = wsI[OFF_COUNTS + b*32 + (t - 128)];
  __syncthreads();
  const uint4 o4 = ((const uint4*)out)[q];
  const unsigned int clsw = ((const unsigned int*)((const char*)wsI + (size_t)OFF_SEGCLS*4))[q];
  uint4 i4, c4;
  {
    const int o = (int)o4.x;
    if (o < ND) { const int v = s_val[o]; i4.x = v & 0xffff; c4.x = v >> 16; }
    else { i4.x = (unsigned)-1; const int cl = clsw & 0xff;
           c4.x = (cl >= 2 && s_cnt[cl] > 4096) ? cl + 90 : 0; }
  }
  {
    const int o = (int)o4.y;
    if (o < ND) { const int v = s_val[o]; i4.y = v & 0xffff; c4.y = v >> 16; }
    else { i4.y = (unsigned)-1; const int cl = (clsw >> 8) & 0xff;
           c4.y = (cl >= 2 && s_cnt[cl] > 4096) ? cl + 90 : 0; }
  }
  {
    const int o = (int)o4.z;
    if (o < ND) { const int v = s_val[o]; i4.z = v & 0xffff; c4.z = v >> 16; }
    else { i4.z = (unsigned)-1; const int cl = (clsw >> 16) & 0xff;
           c4.z = (cl >= 2 && s_cnt[cl] > 4096) ? cl + 90 : 0; }
  }
  {
    const int o = (int)o4.w;
    if (o < ND) { const int v = s_val[o]; i4.w = v & 0xffff; c4.w = v >> 16; }
    else { i4.w = (unsigned)-1; const int cl = (clsw >> 24) & 0xff;
           c4.w = (cl >= 2 && s_cnt[cl] > 4096) ? cl + 90 : 0; }
  }
  ((uint4*)out)[q] = i4;
  ((uint4*)(out + NB*OH*OW))[q] = c4;
}

extern "C" void kernel_launch(void* const* d_in, const int* in_sizes, int n_in,
                              void* d_out, int out_size, void* d_ws, size_t ws_size,
                              hipStream_t stream) {
  const float* boxes   = (const float*)d_in[0];
  const int*   classes = (const int*)d_in[1];
  const float* scores  = (const float*)d_in[2];
  const float* dmasks  = (const float*)d_in[3];
  const float* segp    = (const float*)d_in[4];
  int* wsI = (int*)d_ws;
  int* out = (int*)d_out;

  k_segmask<<<128 + NB*ND, 1024, 0, stream>>>(boxes, classes, scores, dmasks, segp, wsI, out);
  k_scan   <<<NB + NHIST, 64, 0, stream>>>(wsI);
  k_paint  <<<NB*ND, 1024, 0, stream>>>(wsI, out);
  k_resolve<<<(NB*OH*OW)/1024, 256, 0, stream>>>(wsI, out);
}